// Round 8
// baseline (4172.570 us; speedup 1.0000x reference)
//
#include <hip/hip_runtime.h>
#include <math.h>

// ---------------- problem constants ----------------
constexpr int Zd = 256, Tt = 16, NF = 512, Hh = 512, NL = 9, Bb = 1024;
constexpr int BT = Bb * Tt; // 16384
constexpr float LOG_SQRT_2PI_F = 0.9189385332046727f;

typedef _Float16 f16;
typedef __attribute__((ext_vector_type(2))) _Float16 f16x2;
typedef __attribute__((ext_vector_type(4))) _Float16 f16x4;
typedef __attribute__((ext_vector_type(8))) _Float16 f16x8;
typedef __attribute__((ext_vector_type(4))) float f32x4;

__device__ __forceinline__ bool maskbit(int layer, int k) {
  if (layer == 0) return false;
  return (layer & 1) ? ((k & 1) != 0) : ((k & 1) == 0);
}

__device__ __forceinline__ void gld16(void* lds, const void* g) {
  __builtin_amdgcn_global_load_lds(
      (const __attribute__((address_space(1))) void*)g,
      (__attribute__((address_space(3))) void*)lds, 16, 0, 0);
}

__device__ __forceinline__ float fsig(float x) {
  return __builtin_amdgcn_rcpf(1.f + __expf(-x));
}
__device__ __forceinline__ float ftanhf(float x) {
  const float e = __expf(2.f * x);
  return 1.f - 2.f * __builtin_amdgcn_rcpf(e + 1.f);
}

enum { EPI_LEAKY = 0, EPI_S = 1, EPI_T = 2, EPI_MV = 3 };

template <int EPI>
__device__ __forceinline__ void epilogue128(const f32x4 (&acc)[4][4],
                                            const float* __restrict__ bias,
                                            void* __restrict__ C0, int ldc,
                                            int layer, int bm, int bn, int wr,
                                            int wc, int l15, int l4) {
#pragma unroll
  for (int i = 0; i < 4; ++i) {
    const int row0 = bm + wr + 16 * i + l4 * 4;
#pragma unroll
    for (int j = 0; j < 4; ++j) {
      const int col = bn + wc + 16 * j + l15;
#pragma unroll
      for (int r = 0; r < 4; ++r) {
        float v = acc[i][j][r];
        const size_t ci = (size_t)(row0 + r) * ldc + col;
        if (EPI == EPI_LEAKY) {
          v += bias[col];
          v = v > 0.f ? v : 0.01f * v;
          ((f16*)C0)[ci] = (f16)v;
        } else if (EPI == EPI_S) {
          v = ftanhf(v + bias[col]);
          if (maskbit(layer, col)) v = 0.f;
          ((f16*)C0)[ci] = (f16)v;
        } else if (EPI == EPI_T) {
          v += bias[col];
          if (maskbit(layer, col)) v = 0.f;
          ((f16*)C0)[ci] = (f16)v;
        } else { // EPI_MV
          ((f16*)C0)[ci] = (f16)(v + bias[col]);
        }
      }
    }
  }
}

// Dual GEMM: blockIdx.z selects parameter set. C = epi(A[M,K(lda)] @ W[N,K(ldw)]^T)
// 128x128 tile, BK=32, 4 waves, 2-phase prefetch double-buffered LDS.
template <int EPI0, int EPI1>
__global__ __launch_bounds__(256, 4)
void hgemm2_k(const f16* __restrict__ A0, const f16* __restrict__ A1, int lda,
              const f16* __restrict__ W0, const f16* __restrict__ W1, int K, int ldw,
              const float* __restrict__ b0, const float* __restrict__ b1,
              void* __restrict__ C0v, void* __restrict__ C1v, int ldc, int layer)
{
  __shared__ f16 As[2][128][32];
  __shared__ f16 Bs[2][128][32];
  const int zsel = blockIdx.z;
  const f16* A = zsel ? A1 : A0;
  const f16* W = zsel ? W1 : W0;
  const float* bias = zsel ? b1 : b0;
  void* Cv = zsel ? C1v : C0v;

  const int bm = blockIdx.x * 128;
  const int bn = blockIdx.y * 128;
  const int tid = threadIdx.x;
  const int lane = tid & 63;
  const int wid = tid >> 6;
  const int wr = (wid >> 1) * 64;
  const int wc = (wid & 1) * 64;
  const int l15 = lane & 15;
  const int l4 = lane >> 4;
  const int arow = tid >> 2;
  const int akb = (tid & 3) * 16;

  const char* Ab = (const char*)A + (size_t)(bm + arow) * lda * 2 + akb;
  const char* Wb = (const char*)W + (size_t)(bn + arow) * ldw * 2 + akb;

  auto stage = [&](int buf, int k0) {
    const size_t kb = (size_t)k0 * 2;
    char* la = (char*)&As[buf][0][0];
    char* lb = (char*)&Bs[buf][0][0];
    gld16(la + tid * 16, Ab + kb);
    gld16(la + 4096 + tid * 16, Ab + kb + (size_t)lda * 128);
    gld16(lb + tid * 16, Wb + kb);
    gld16(lb + 4096 + tid * 16, Wb + kb + (size_t)ldw * 128);
  };

  f32x4 acc[4][4] = {};
  const int nk = K >> 5;
  stage(0, 0);
  __syncthreads();

  for (int t = 0; t < nk; ++t) {
    const int cur = t & 1;
    if (t + 1 < nk) stage(cur ^ 1, (t + 1) << 5);
    f16x8 af[4], bf[4];
#pragma unroll
    for (int i = 0; i < 4; ++i) af[i] = *(const f16x8*)&As[cur][wr + 16 * i + l15][l4 * 8];
#pragma unroll
    for (int j = 0; j < 4; ++j) bf[j] = *(const f16x8*)&Bs[cur][wc + 16 * j + l15][l4 * 8];
#pragma unroll
    for (int i = 0; i < 4; ++i)
#pragma unroll
      for (int j = 0; j < 4; ++j)
        acc[i][j] = __builtin_amdgcn_mfma_f32_16x16x32_f16(af[i], bf[j], acc[i][j], 0, 0, 0);
    __syncthreads();
  }

  if (zsel == 0)
    epilogue128<EPI0>(acc, bias, Cv, ldc, layer, bm, bn, wr, wc, l15, l4);
  else
    epilogue128<EPI1>(acc, bias, Cv, ldc, layer, bm, bn, wr, wc, l15, l4);
}

// ---------------- persistent LSTM ----------------
// grid barrier: epoch counting, agent scope. All threads fence their own
// stores to device scope, then thread 0 release-adds and acquire-spins.
__device__ __forceinline__ void gbar(unsigned* cnt, unsigned& epoch, int nblk) {
  __threadfence();
  __syncthreads();
  if (threadIdx.x == 0) {
    __hip_atomic_fetch_add(cnt, 1u, __ATOMIC_ACQ_REL, __HIP_MEMORY_SCOPE_AGENT);
    epoch += (unsigned)nblk;
    while (__hip_atomic_load(cnt, __ATOMIC_RELAXED, __HIP_MEMORY_SCOPE_AGENT) < epoch)
      __builtin_amdgcn_s_sleep(2);
    (void)__hip_atomic_load(cnt, __ATOMIC_ACQUIRE, __HIP_MEMORY_SCOPE_AGENT);
  }
  __syncthreads();
}

// All 16 LSTM steps in one kernel. 256 blocks (deadlock-safe: <= #CUs, and
// resources allow 2 blocks/CU) = 16 m-tiles x 16 n-pairs; each block owns a
// 64-row x 128-col slice of the [1024 x 2048] gate matrix (2 n-tiles).
// BK=64, 2-phase prefetch, source-swizzled staging (chunk sp ^ (row&7)) so
// ds_read_b128 frag reads are ~conflict-free. Gate-interleaved weights
// (col n = 4*unit+gate, order i,f,g,o); 3x shfl_xor butterfly; lanes with
// n%4==0 update c and write h.
__global__ __launch_bounds__(256, 2)
void lstm_k(const f16* __restrict__ P1, const f16* __restrict__ whh1i,
            const f16* __restrict__ wc2i, const float* __restrict__ bsum2,
            float* __restrict__ c1, float* __restrict__ c2,
            f16* __restrict__ h1a, f16* __restrict__ h1b,
            f16* __restrict__ h2a, f16* __restrict__ h2b,
            f16* __restrict__ hall, unsigned* __restrict__ bar)
{
  __shared__ f16 As[2][64][64];
  __shared__ f16 Bs[2][2][64][64];
  const int bid = blockIdx.x;
  const int bm = (bid >> 4) * 64;    // 16 m-tiles
  const int bn0 = (bid & 15) * 128;  // 16 n-pairs
  const int tid = threadIdx.x;
  const int lane = tid & 63;
  const int wid = tid >> 6;
  const int l15 = lane & 15;
  const int l4 = lane >> 4;
  const int sr0 = tid >> 3;   // stage row 0..31 (+32 round 1)
  const int sp = tid & 7;     // stage chunk slot
  unsigned epoch = 0;

  // lane-constant swizzled frag-read byte offsets (within a 64x64 f16 tile)
  int offA[4][2], offB[2];
#pragma unroll
  for (int i = 0; i < 4; ++i)
#pragma unroll
    for (int h = 0; h < 2; ++h)
      offA[i][h] = (16 * i + l15) * 128 + (((l4 + 4 * h) ^ (l15 & 7)) * 16);
#pragma unroll
  for (int h = 0; h < 2; ++h)
    offB[h] = (wid * 16 + l15) * 128 + (((l4 + 4 * h) ^ (l15 & 7)) * 16);

  const int nn[2] = {bn0 + wid * 16 + l15, bn0 + 64 + wid * 16 + l15};

  for (int t = 0; t < Tt; ++t) {
    const f16* h1p = (t & 1) ? h1b : h1a;
    f16* h1n = (t & 1) ? h1a : h1b;
    const f16* h2p = (t & 1) ? h2b : h2a;
    f16* h2n = (t & 1) ? h2a : h2b;

    // ---- phase 1: gates1 = h1p @ whh1i^T + P1[t] -> cell1 -> h1n, c1 ----
    {
      auto stage = [&](int buf, int k0) {
#pragma unroll
        for (int rnd = 0; rnd < 2; ++rnd) {
          const int r = sr0 + 32 * rnd;
          const int gc = (sp ^ (r & 7)) * 16;
          gld16((char*)&As[buf][0][0] + rnd * 4096 + tid * 16,
                (const char*)h1p + ((size_t)(bm + r) * 512 + k0) * 2 + gc);
          gld16((char*)&Bs[buf][0][0][0] + rnd * 4096 + tid * 16,
                (const char*)whh1i + ((size_t)(bn0 + r) * 512 + k0) * 2 + gc);
          gld16((char*)&Bs[buf][1][0][0] + rnd * 4096 + tid * 16,
                (const char*)whh1i + ((size_t)(bn0 + 64 + r) * 512 + k0) * 2 + gc);
        }
      };
      f32x4 acc[2][4] = {};
      stage(0, 0);
      __syncthreads();
      for (int it = 0; it < 8; ++it) {
        const int cur = it & 1;
        if (it + 1 < 8) stage(cur ^ 1, (it + 1) * 64);
        const char* la = (const char*)&As[cur][0][0];
#pragma unroll
        for (int h = 0; h < 2; ++h) {
          f16x8 af[4];
#pragma unroll
          for (int i = 0; i < 4; ++i) af[i] = *(const f16x8*)(la + offA[i][h]);
#pragma unroll
          for (int j = 0; j < 2; ++j) {
            const f16x8 bf = *(const f16x8*)((const char*)&Bs[cur][j][0][0] + offB[h]);
#pragma unroll
            for (int i = 0; i < 4; ++i)
              acc[j][i] = __builtin_amdgcn_mfma_f32_16x16x32_f16(af[i], bf, acc[j][i], 0, 0, 0);
          }
        }
        __syncthreads();
      }
      const f16* P1t = P1 + (size_t)t * 1024 * 2048;
#pragma unroll
      for (int j = 0; j < 2; ++j) {
        const int n = nn[j];
        const int g0 = n & 3, jj = n >> 2;
#pragma unroll
        for (int i = 0; i < 4; ++i) {
          const int row0 = bm + 16 * i + l4 * 4;
#pragma unroll
          for (int r = 0; r < 4; ++r) {
            float v = acc[j][i][r] + (float)P1t[(size_t)(row0 + r) * 2048 + n];
            const float a1 = __shfl_xor(v, 1);
            const float a2 = __shfl_xor(v, 2);
            const float a3 = __shfl_xor(v, 3);
            if (g0 == 0) {
              const size_t ci = (size_t)(row0 + r) * 512 + jj;
              const float cv = fsig(a1) * c1[ci] + fsig(v) * ftanhf(a2);
              const float h = fsig(a3) * ftanhf(cv);
              c1[ci] = cv;
              h1n[ci] = (f16)h;
            }
          }
        }
      }
    }
    gbar(bar, epoch, 256);

    // ---- phase 2: gates2 = [h1n | h2p] @ wc2i^T + bsum2 -> cell2 ----
    {
      auto stage = [&](int buf, int k0) {
#pragma unroll
        for (int rnd = 0; rnd < 2; ++rnd) {
          const int r = sr0 + 32 * rnd;
          const int gc = (sp ^ (r & 7)) * 16;
          const char* asrc = (k0 < 512)
              ? (const char*)h1n + ((size_t)(bm + r) * 512 + k0) * 2
              : (const char*)h2p + ((size_t)(bm + r) * 512 + (k0 - 512)) * 2;
          gld16((char*)&As[buf][0][0] + rnd * 4096 + tid * 16, asrc + gc);
          gld16((char*)&Bs[buf][0][0][0] + rnd * 4096 + tid * 16,
                (const char*)wc2i + ((size_t)(bn0 + r) * 1024 + k0) * 2 + gc);
          gld16((char*)&Bs[buf][1][0][0] + rnd * 4096 + tid * 16,
                (const char*)wc2i + ((size_t)(bn0 + 64 + r) * 1024 + k0) * 2 + gc);
        }
      };
      f32x4 acc[2][4] = {};
      stage(0, 0);
      __syncthreads();
      for (int it = 0; it < 16; ++it) {
        const int cur = it & 1;
        if (it + 1 < 16) stage(cur ^ 1, (it + 1) * 64);
        const char* la = (const char*)&As[cur][0][0];
#pragma unroll
        for (int h = 0; h < 2; ++h) {
          f16x8 af[4];
#pragma unroll
          for (int i = 0; i < 4; ++i) af[i] = *(const f16x8*)(la + offA[i][h]);
#pragma unroll
          for (int j = 0; j < 2; ++j) {
            const f16x8 bf = *(const f16x8*)((const char*)&Bs[cur][j][0][0] + offB[h]);
#pragma unroll
            for (int i = 0; i < 4; ++i)
              acc[j][i] = __builtin_amdgcn_mfma_f32_16x16x32_f16(af[i], bf, acc[j][i], 0, 0, 0);
          }
        }
        __syncthreads();
      }
#pragma unroll
      for (int j = 0; j < 2; ++j) {
        const int n = nn[j];
        const int g0 = n & 3, jj = n >> 2;
#pragma unroll
        for (int i = 0; i < 4; ++i) {
          const int row0 = bm + 16 * i + l4 * 4;
#pragma unroll
          for (int r = 0; r < 4; ++r) {
            float v = acc[j][i][r] + bsum2[n];
            const float a1 = __shfl_xor(v, 1);
            const float a2 = __shfl_xor(v, 2);
            const float a3 = __shfl_xor(v, 3);
            if (g0 == 0) {
              const size_t ci = (size_t)(row0 + r) * 512 + jj;
              const float cv = fsig(a1) * c2[ci] + fsig(v) * ftanhf(a2);
              const float h = fsig(a3) * ftanhf(cv);
              c2[ci] = cv;
              h2n[ci] = (f16)h;
              hall[((size_t)t * 1024 + row0 + r) * 512 + jj] = (f16)h;
            }
          }
        }
      }
    }
    gbar(bar, epoch, 256);
  }
}

// ---------------- elementwise / reductions ----------------

__device__ __forceinline__ double block_reduce_d(double v) {
  __shared__ double sred[4];
#pragma unroll
  for (int off = 32; off > 0; off >>= 1) v += __shfl_down(v, off);
  const int lane = threadIdx.x & 63;
  const int w = threadIdx.x >> 6;
  if (lane == 0) sred[w] = v;
  __syncthreads();
  double r = 0.0;
  if (threadIdx.x == 0) {
    const int nw = blockDim.x >> 6;
    r = sred[0];
    for (int i = 1; i < nw; ++i) r += sred[i];
  }
  return r;
}

// z fp32; inp384 = [z_active(128) | p(256)] for layer 8 (even k); inp512 p-half
__global__ __launch_bounds__(256)
void split_k(const float* __restrict__ nf, float* __restrict__ z,
             f16* __restrict__ inp384, f16* __restrict__ inp512) {
  const int n = BT * Zd;
  for (int i = blockIdx.x * blockDim.x + threadIdx.x; i < n; i += gridDim.x * blockDim.x) {
    const int m = i >> 8, k = i & 255;
    const float pv = nf[(size_t)m * 512 + k];
    const float zv = nf[(size_t)m * 512 + 256 + k];
    z[(size_t)m * 256 + k] = zv;
    inp512[(size_t)m * 512 + 256 + k] = (f16)pv;
    inp384[(size_t)m * 384 + 128 + k] = (f16)pv;
    if ((k & 1) == 0) inp384[(size_t)m * 384 + (k >> 1)] = (f16)zv;  // layer 8: even kept
  }
}

// one wave per row (4 rows/block). LAST=0: z update + ldj + compact next z-half.
// LAST=1 (layer 0): final update -> out[1..], logN(z3) into acc[1], xbuf slabs.
template <int LAST>
__global__ __launch_bounds__(256)
void flow_update_k(float* __restrict__ z, const f16* __restrict__ s16,
                   const f16* __restrict__ t16, float* __restrict__ ldj,
                   f16* __restrict__ inp384, int layer, int nextlayer,
                   float* __restrict__ out, f16* __restrict__ xbuf,
                   double* __restrict__ acc) {
  const int w = threadIdx.x >> 6, lane = threadIdx.x & 63;
  const int m = blockIdx.x * 4 + w;
  const int k0 = lane * 4;
  const size_t base = (size_t)m * 256 + k0;
  const float4 zv = *(const float4*)(z + base);
  const f16x4 sv = *(const f16x4*)(s16 + base);
  const f16x4 tv = *(const f16x4*)(t16 + base);
  float zr[4] = {zv.x, zv.y, zv.z, zv.w};
  float ssum = 0.f;
  float zn[4];
#pragma unroll
  for (int e = 0; e < 4; ++e) {
    const float s = (float)sv[e];
    ssum += s;
    zn[e] = maskbit(layer, k0 + e) ? zr[e] : (zr[e] - (float)tv[e]) * __expf(-s);
  }
  if (!LAST) {
    *(float4*)(z + base) = make_float4(zn[0], zn[1], zn[2], zn[3]);
    if (nextlayer > 0) {
      const int par = nextlayer & 1;  // odd layer keeps odd k
      f16x2 o;
      o[0] = (f16)zn[par];
      o[1] = (f16)zn[par + 2];
      *(f16x2*)(inp384 + (size_t)m * 384 + (k0 >> 1)) = o;
    }
  } else {
    // out (offset 1, scalar stores), xbuf slab t+1, logN accumulation
#pragma unroll
    for (int e = 0; e < 4; ++e) out[1 + base + e] = zn[e];
    const int b = m >> 4, tt = m & 15;
    if (tt < 15) {
      f16x4 xo;
#pragma unroll
      for (int e = 0; e < 4; ++e) xo[e] = (f16)zn[e];
      *(f16x4*)(xbuf + (((size_t)(tt + 1) << 10) + b) * 256 + k0) = xo;
    }
    double ln = 0.0;
#pragma unroll
    for (int e = 0; e < 4; ++e)
      ln += (double)(-0.5f * zn[e] * zn[e] - LOG_SQRT_2PI_F);
#pragma unroll
    for (int off = 32; off > 0; off >>= 1) ln += __shfl_down(ln, off);
    __shared__ double lred[4];
    if (lane == 0) lred[w] = ln;
    __syncthreads();
    if (threadIdx.x == 0)
      atomicAdd(acc + 1, lred[0] + lred[1] + lred[2] + lred[3]);
  }
#pragma unroll
  for (int off = 32; off > 0; off >>= 1) ssum += __shfl_down(ssum, off);
  if (lane == 0) ldj[m] -= ssum;
}

// layer-0 input: z_shift into inp512 z-half
__global__ __launch_bounds__(256)
void prep0_k(const float* __restrict__ z, f16* __restrict__ inp512) {
  const int n = BT * Zd;
  for (int i = blockIdx.x * blockDim.x + threadIdx.x; i < n; i += gridDim.x * blockDim.x) {
    const int m = i >> 8, k = i & 255;
    const float v = ((m & 15) == 0) ? 0.f : z[(size_t)(m - 1) * 256 + k];
    inp512[(size_t)m * 512 + k] = (f16)v;
  }
}

__global__ __launch_bounds__(256)
void ldj_sum_k(const float* __restrict__ ldj, double* __restrict__ acc) {
  double local = 0.0;
  for (int i = blockIdx.x * blockDim.x + threadIdx.x; i < BT; i += gridDim.x * blockDim.x)
    local += (double)ldj[i];
  local = block_reduce_d(local);
  if (threadIdx.x == 0) atomicAdd(acc + 1, local);
}

// z3 read from out[1..]
__global__ __launch_bounds__(256)
void post_all_k(const f16* __restrict__ mv, const float* __restrict__ out,
                double* __restrict__ acc) {
  const int n = BT * Zd;
  double local = 0.0;
  for (int i = blockIdx.x * blockDim.x + threadIdx.x; i < n; i += gridDim.x * blockDim.x) {
    const int k = i & 255;
    const int row = i >> 8;               // t*1024 + b
    const int t = row >> 10, b = row & 1023;
    const float mean = (float)mv[(size_t)row * 512 + k];
    const float lv = (float)mv[(size_t)row * 512 + 256 + k];
    const float zv = out[1 + ((size_t)b * 16 + t) * 256 + k];
    const float d = (zv - mean) * __expf(-lv);
    local += (double)(-0.5f * d * d - LOG_SQRT_2PI_F) - (double)lv;
  }
  local = block_reduce_d(local);
  if (threadIdx.x == 0) atomicAdd(acc + 0, local);
}

__global__ void finalize_k(const double* __restrict__ acc, float* __restrict__ out) {
  const double loglik = 0.0025 * acc[0] + acc[1];
  out[0] = (float)(-loglik / (double)Bb);
}

// ---------------- weight conversion ----------------
__global__ __launch_bounds__(256)
void cvt_k(const float* __restrict__ s, f16* __restrict__ d, int n) {
  for (int i = blockIdx.x * blockDim.x + threadIdx.x; i < n; i += gridDim.x * blockDim.x)
    d[i] = (f16)s[i];
}

__global__ __launch_bounds__(256)
void cvt_cat_rows_k(const float* __restrict__ a, const float* __restrict__ b,
                    f16* __restrict__ d, int L, int R, int K) {
  const int n = L * 2 * R * K;
  for (int i = blockIdx.x * blockDim.x + threadIdx.x; i < n; i += gridDim.x * blockDim.x) {
    const int k = i % K;
    const int rem = i / K;
    const int r = rem % (2 * R);
    const int l = rem / (2 * R);
    const float v = (r < R) ? a[((size_t)l * R + r) * K + k]
                            : b[((size_t)l * R + (r - R)) * K + k];
    d[i] = (f16)v;
  }
}

// w1a[1024][512] (layer 0 full) + w1b[8][1024][384] (layers 1..8, z-cols gathered)
__global__ __launch_bounds__(256)
void cvt_w1_k(const float* __restrict__ sW1, const float* __restrict__ tW1,
              f16* __restrict__ w1a, f16* __restrict__ w1b) {
  const int N0 = 1024 * 512;
  const int N1 = 8 * 1024 * 384;
  for (int i = blockIdx.x * blockDim.x + threadIdx.x; i < N0 + N1; i += gridDim.x * blockDim.x) {
    if (i < N0) {
      const int r = i / 512, k = i % 512;
      const float* S = (r < 512) ? sW1 : tW1;
      w1a[i] = (f16)S[(size_t)(r & 511) * 512 + k];
    } else {
      const int jj = i - N0;
      const int k = jj % 384;
      const int r = (jj / 384) & 1023;
      const int l = jj / (384 * 1024) + 1;
      const int col = (k < 128) ? (2 * k + (l & 1)) : (k + 128);
      const float* S = (r < 512) ? sW1 : tW1;
      w1b[jj] = (f16)S[((size_t)l * 512 + (r & 511)) * 512 + col];
    }
  }
}

// gate-interleaved fp16: d[n][k], K=ka+kb, old row = (n&3)*512 + (n>>2)
__global__ __launch_bounds__(256)
void cvt_int_k(const float* __restrict__ a, int ka, const float* __restrict__ b,
               int kb, f16* __restrict__ d, int N) {
  const int K = ka + kb;
  const int n_tot = N * K;
  for (int i = blockIdx.x * blockDim.x + threadIdx.x; i < n_tot; i += gridDim.x * blockDim.x) {
    const int k = i % K;
    const int n = i / K;
    const int row = (n & 3) * 512 + (n >> 2);
    const float v = (k < ka) ? a[(size_t)row * ka + k] : b[(size_t)row * kb + (k - ka)];
    d[i] = (f16)v;
  }
}

__global__ __launch_bounds__(256)
void bsum_int_k(const float* __restrict__ bih, const float* __restrict__ bhh,
                float* __restrict__ d) {
  const int i = blockIdx.x * blockDim.x + threadIdx.x;
  if (i < 2048) {
    const int row = (i & 3) * 512 + (i >> 2);
    d[i] = bih[row] + bhh[row];
  }
}

__global__ __launch_bounds__(256)
void fcat_k(const float* __restrict__ a, const float* __restrict__ b,
            float* __restrict__ d, int L, int R) {
  const int n = L * 2 * R;
  for (int i = blockIdx.x * blockDim.x + threadIdx.x; i < n; i += gridDim.x * blockDim.x) {
    const int c = i % (2 * R);
    const int l = i / (2 * R);
    d[i] = (c < R) ? a[(size_t)l * R + c] : b[(size_t)l * R + (c - R)];
  }
}

// ---------------- host launch ----------------
extern "C" void kernel_launch(void* const* d_in, const int* in_sizes, int n_in,
                              void* d_out, int out_size, void* d_ws, size_t ws_size,
                              hipStream_t stream) {
  (void)in_sizes; (void)n_in; (void)out_size; (void)ws_size;

  const float* nf    = (const float*)d_in[0];
  const float* sW1   = (const float*)d_in[1];
  const float* sb1   = (const float*)d_in[2];
  const float* sW2   = (const float*)d_in[3];
  const float* sb2   = (const float*)d_in[4];
  const float* sW3   = (const float*)d_in[5];
  const float* sb3   = (const float*)d_in[6];
  const float* tW1   = (const float*)d_in[7];
  const float* tb1   = (const float*)d_in[8];
  const float* tW2   = (const float*)d_in[9];
  const float* tb2   = (const float*)d_in[10];
  const float* tW3   = (const float*)d_in[11];
  const float* tb3   = (const float*)d_in[12];
  const float* l1Wih = (const float*)d_in[13];
  const float* l1Whh = (const float*)d_in[14];
  const float* l1bih = (const float*)d_in[15];
  const float* l1bhh = (const float*)d_in[16];
  const float* l2Wih = (const float*)d_in[17];
  const float* l2Whh = (const float*)d_in[18];
  const float* l2bih = (const float*)d_in[19];
  const float* l2bhh = (const float*)d_in[20];
  const float* mW    = (const float*)d_in[21];
  const float* mb    = (const float*)d_in[22];
  const float* lvW   = (const float*)d_in[23];
  const float* lvb   = (const float*)d_in[24];

  float* out = (float*)d_out;

  char* wsb = (char*)d_ws;
  size_t off = 0;
  auto alloc = [&](size_t bytes) -> char* {
    char* p = wsb + off;
    off += (bytes + 255) & ~(size_t)255;
    return p;
  };
  double*   acc    = (double*)alloc(32);          // acc[0], acc[1], bar
  unsigned* bar    = (unsigned*)(acc + 2);
  float*  z      = (float*)alloc((size_t)BT * Zd * 4);
  f16*    inp512 = (f16*)alloc((size_t)BT * 512 * 2);   // LSTM: mvbuf
  f16*    inp384 = (f16*)alloc((size_t)BT * 384 * 2);   // LSTM: xbuf (first 8MB)
  f16*    hidA   = (f16*)alloc((size_t)BT * 1024 * 2);  // LSTM: P1 (spans hidA+hidB)
  f16*    hidB   = (f16*)alloc((size_t)BT * 1024 * 2);
  f16*    s16b   = (f16*)alloc((size_t)BT * Zd * 2);    // LSTM: h1a,h1b,h2a,h2b
  f16*    t16b   = (f16*)alloc((size_t)BT * Zd * 2);    // LSTM: c1,c2 (fp32)
  f16*    hall   = (f16*)alloc((size_t)BT * 512 * 2);
  float*  ldj    = (float*)alloc((size_t)BT * 4);
  f16* w1a   = (f16*)alloc((size_t)1024 * 512 * 2);
  f16* w1b   = (f16*)alloc((size_t)8 * 1024 * 384 * 2);
  f16* w2s   = (f16*)alloc((size_t)9 * 512 * 512 * 2);
  f16* w2t   = (f16*)alloc((size_t)9 * 512 * 512 * 2);
  f16* w3s   = (f16*)alloc((size_t)9 * 256 * 512 * 2);
  f16* w3t   = (f16*)alloc((size_t)9 * 256 * 512 * 2);
  f16* wih1i = (f16*)alloc((size_t)2048 * 256 * 2);
  f16* whh1i = (f16*)alloc((size_t)2048 * 512 * 2);
  f16* wc2i  = (f16*)alloc((size_t)2048 * 1024 * 2);
  f16* wmv   = (f16*)alloc((size_t)512 * 512 * 2);
  float* bcat1 = (float*)alloc((size_t)9 * 1024 * 4);
  float* bsum1 = (float*)alloc((size_t)2048 * 4);
  float* bsum2 = (float*)alloc((size_t)2048 * 4);
  float* bmv   = (float*)alloc((size_t)512 * 4);

  // LSTM-phase aliases
  f16*   xbuf  = inp384;                                 // [16][1024][256]
  f16*   P1    = hidA;                                   // [16384][2048]
  f16*   h1a   = s16b;                                   // 4 x [1024][512] f16
  f16*   h1b   = h1a + (size_t)1024 * 512;
  f16*   h2a   = h1b + (size_t)1024 * 512;
  f16*   h2b   = h2a + (size_t)1024 * 512;
  float* c1    = (float*)t16b;                           // 2 x [1024][512] fp32
  float* c2    = c1 + (size_t)1024 * 512;
  f16*   mvbuf = inp512;                                 // [16384][512]

  // ---- weight conversions ----
  cvt_w1_k<<<2048, 256, 0, stream>>>(sW1, tW1, w1a, w1b);
  cvt_k<<<2048, 256, 0, stream>>>(sW2, w2s, 9 * 512 * 512);
  cvt_k<<<2048, 256, 0, stream>>>(tW2, w2t, 9 * 512 * 512);
  cvt_k<<<1024, 256, 0, stream>>>(sW3, w3s, 9 * 256 * 512);
  cvt_k<<<1024, 256, 0, stream>>>(tW3, w3t, 9 * 256 * 512);
  cvt_int_k<<<1024, 256, 0, stream>>>(l1Wih, 256, l1Wih, 0, wih1i, 2048);
  cvt_int_k<<<1024, 256, 0, stream>>>(l1Whh, 512, l1Whh, 0, whh1i, 2048);
  cvt_int_k<<<1024, 256, 0, stream>>>(l2Wih, 512, l2Whh, 512, wc2i, 2048);
  cvt_cat_rows_k<<<256, 256, 0, stream>>>(mW, lvW, wmv, 1, 256, 512);
  fcat_k<<<16, 256, 0, stream>>>(sb1, tb1, bcat1, 9, 512);
  bsum_int_k<<<8, 256, 0, stream>>>(l1bih, l1bhh, bsum1);
  bsum_int_k<<<8, 256, 0, stream>>>(l2bih, l2bhh, bsum2);
  fcat_k<<<2, 256, 0, stream>>>(mb, lvb, bmv, 1, 256);

  hipMemsetAsync(acc, 0, 32, stream);   // acc + bar
  hipMemsetAsync(ldj, 0, (size_t)BT * 4, stream);

  split_k<<<2048, 256, 0, stream>>>(nf, z, inp384, inp512);

  // ---- inverse flow: layers 8..0 ----
  for (int i = NL - 1; i >= 0; --i) {
    if (i == 0)
      hgemm2_k<EPI_LEAKY, EPI_LEAKY><<<dim3(128, 8, 1), 256, 0, stream>>>(
          inp512, inp512, 512, w1a, w1a, 512, 512, bcat1, bcat1, hidA, hidA, 1024, 0);
    else
      hgemm2_k<EPI_LEAKY, EPI_LEAKY><<<dim3(128, 8, 1), 256, 0, stream>>>(
          inp384, inp384, 384, w1b + (size_t)(i - 1) * 1024 * 384,
          w1b + (size_t)(i - 1) * 1024 * 384, 384, 384,
          bcat1 + i * 1024, bcat1 + i * 1024, hidA, hidA, 1024, 0);
    hgemm2_k<EPI_LEAKY, EPI_LEAKY><<<dim3(128, 4, 2), 256, 0, stream>>>(
        hidA, hidA + 512, 1024, w2s + (size_t)i * 512 * 512, w2t + (size_t)i * 512 * 512,
        512, 512, sb2 + i * 512, tb2 + i * 512, hidB, hidB + 512, 1024, 0);
    hgemm2_k<EPI_S, EPI_T><<<dim3(128, 2, 2), 256, 0, stream>>>(
        hidB, hidB + 512, 1024, w3s + (size_t)i * 256 * 512, w3t + (size_t)i * 256 * 512,
        512, 512, sb3 + i * 256, tb3 + i * 256, s16b, t16b, 256, i);
    if (i > 0) {
      flow_update_k<0><<<BT / 4, 256, 0, stream>>>(
          z, s16b, t16b, ldj, inp384, i, i - 1, nullptr, nullptr, nullptr);
      if (i - 1 == 0) prep0_k<<<2048, 256, 0, stream>>>(z, inp512);
    } else {
      flow_update_k<1><<<BT / 4, 256, 0, stream>>>(
          z, s16b, t16b, ldj, nullptr, 0, -1, out, xbuf, acc);
    }
  }

  ldj_sum_k<<<64, 256, 0, stream>>>(ldj, acc);

  // ---- LSTM prior ----
  hipMemsetAsync(h1a, 0, (size_t)4 * 1024 * 512 * 2, stream);   // h1a,h1b,h2a,h2b
  hipMemsetAsync(c1, 0, (size_t)2 * 1024 * 512 * 4, stream);    // c1,c2
  hipMemsetAsync(xbuf, 0, (size_t)1024 * 256 * 2, stream);      // t=0 slab
  hgemm2_k<EPI_MV, EPI_MV><<<dim3(128, 16, 1), 256, 0, stream>>>(
      xbuf, xbuf, 256, wih1i, wih1i, 256, 256, bsum1, bsum1, P1, P1, 2048, 0);
  lstm_k<<<256, 256, 0, stream>>>(P1, whh1i, wc2i, bsum2, c1, c2,
                                  h1a, h1b, h2a, h2b, hall, bar);

  hgemm2_k<EPI_MV, EPI_MV><<<dim3(128, 4, 1), 256, 0, stream>>>(
      hall, hall, 512, wmv, wmv, 512, 512, bmv, bmv, mvbuf, mvbuf, 512, 0);
  post_all_k<<<1024, 256, 0, stream>>>(mvbuf, out, acc);

  finalize_k<<<1, 1, 0, stream>>>(acc, out);
}

// Round 9
// 3738.944 us; speedup vs baseline: 1.1160x; 1.1160x over previous
//
#include <hip/hip_runtime.h>
#include <math.h>

// ---------------- problem constants ----------------
constexpr int Zd = 256, Tt = 16, NF = 512, Hh = 512, NL = 9, Bb = 1024;
constexpr int BT = Bb * Tt; // 16384
constexpr float LOG_SQRT_2PI_F = 0.9189385332046727f;

typedef _Float16 f16;
typedef __attribute__((ext_vector_type(2))) _Float16 f16x2;
typedef __attribute__((ext_vector_type(4))) _Float16 f16x4;
typedef __attribute__((ext_vector_type(8))) _Float16 f16x8;
typedef __attribute__((ext_vector_type(4))) float f32x4;

__device__ __forceinline__ bool maskbit(int layer, int k) {
  if (layer == 0) return false;
  return (layer & 1) ? ((k & 1) != 0) : ((k & 1) == 0);
}

__device__ __forceinline__ void gld16(void* lds, const void* g) {
  __builtin_amdgcn_global_load_lds(
      (const __attribute__((address_space(1))) void*)g,
      (__attribute__((address_space(3))) void*)lds, 16, 0, 0);
}

__device__ __forceinline__ float fsig(float x) {
  return __builtin_amdgcn_rcpf(1.f + __expf(-x));
}
__device__ __forceinline__ float ftanhf(float x) {
  const float e = __expf(2.f * x);
  return 1.f - 2.f * __builtin_amdgcn_rcpf(e + 1.f);
}

enum { EPI_LEAKY = 0, EPI_S = 1, EPI_T = 2, EPI_MV = 3 };

template <int EPI>
__device__ __forceinline__ void epilogue128(const f32x4 (&acc)[4][4],
                                            const float* __restrict__ bias,
                                            void* __restrict__ C0, int ldc,
                                            int layer, int bm, int bn, int wr,
                                            int wc, int l15, int l4) {
#pragma unroll
  for (int i = 0; i < 4; ++i) {
    const int row0 = bm + wr + 16 * i + l4 * 4;
#pragma unroll
    for (int j = 0; j < 4; ++j) {
      const int col = bn + wc + 16 * j + l15;
#pragma unroll
      for (int r = 0; r < 4; ++r) {
        float v = acc[i][j][r];
        const size_t ci = (size_t)(row0 + r) * ldc + col;
        if (EPI == EPI_LEAKY) {
          v += bias[col];
          v = v > 0.f ? v : 0.01f * v;
          ((f16*)C0)[ci] = (f16)v;
        } else if (EPI == EPI_S) {
          v = ftanhf(v + bias[col]);
          if (maskbit(layer, col)) v = 0.f;
          ((f16*)C0)[ci] = (f16)v;
        } else if (EPI == EPI_T) {
          v += bias[col];
          if (maskbit(layer, col)) v = 0.f;
          ((f16*)C0)[ci] = (f16)v;
        } else { // EPI_MV
          ((f16*)C0)[ci] = (f16)(v + bias[col]);
        }
      }
    }
  }
}

// Dual GEMM: blockIdx.z selects parameter set. C = epi(A[M,K(lda)] @ W[N,K(ldw)]^T)
// 128x128 tile, BK=32, 4 waves, 2-phase prefetch double-buffered LDS.
template <int EPI0, int EPI1>
__global__ __launch_bounds__(256, 4)
void hgemm2_k(const f16* __restrict__ A0, const f16* __restrict__ A1, int lda,
              const f16* __restrict__ W0, const f16* __restrict__ W1, int K, int ldw,
              const float* __restrict__ b0, const float* __restrict__ b1,
              void* __restrict__ C0v, void* __restrict__ C1v, int ldc, int layer)
{
  __shared__ f16 As[2][128][32];
  __shared__ f16 Bs[2][128][32];
  const int zsel = blockIdx.z;
  const f16* A = zsel ? A1 : A0;
  const f16* W = zsel ? W1 : W0;
  const float* bias = zsel ? b1 : b0;
  void* Cv = zsel ? C1v : C0v;

  const int bm = blockIdx.x * 128;
  const int bn = blockIdx.y * 128;
  const int tid = threadIdx.x;
  const int lane = tid & 63;
  const int wid = tid >> 6;
  const int wr = (wid >> 1) * 64;
  const int wc = (wid & 1) * 64;
  const int l15 = lane & 15;
  const int l4 = lane >> 4;
  const int arow = tid >> 2;
  const int akb = (tid & 3) * 16;

  const char* Ab = (const char*)A + (size_t)(bm + arow) * lda * 2 + akb;
  const char* Wb = (const char*)W + (size_t)(bn + arow) * ldw * 2 + akb;

  auto stage = [&](int buf, int k0) {
    const size_t kb = (size_t)k0 * 2;
    char* la = (char*)&As[buf][0][0];
    char* lb = (char*)&Bs[buf][0][0];
    gld16(la + tid * 16, Ab + kb);
    gld16(la + 4096 + tid * 16, Ab + kb + (size_t)lda * 128);
    gld16(lb + tid * 16, Wb + kb);
    gld16(lb + 4096 + tid * 16, Wb + kb + (size_t)ldw * 128);
  };

  f32x4 acc[4][4] = {};
  const int nk = K >> 5;
  stage(0, 0);
  __syncthreads();

  for (int t = 0; t < nk; ++t) {
    const int cur = t & 1;
    if (t + 1 < nk) stage(cur ^ 1, (t + 1) << 5);
    f16x8 af[4], bf[4];
#pragma unroll
    for (int i = 0; i < 4; ++i) af[i] = *(const f16x8*)&As[cur][wr + 16 * i + l15][l4 * 8];
#pragma unroll
    for (int j = 0; j < 4; ++j) bf[j] = *(const f16x8*)&Bs[cur][wc + 16 * j + l15][l4 * 8];
#pragma unroll
    for (int i = 0; i < 4; ++i)
#pragma unroll
      for (int j = 0; j < 4; ++j)
        acc[i][j] = __builtin_amdgcn_mfma_f32_16x16x32_f16(af[i], bf[j], acc[i][j], 0, 0, 0);
    __syncthreads();
  }

  if (zsel == 0)
    epilogue128<EPI0>(acc, bias, Cv, ldc, layer, bm, bn, wr, wc, l15, l4);
  else
    epilogue128<EPI1>(acc, bias, Cv, ldc, layer, bm, bn, wr, wc, l15, l4);
}

// ---------------- persistent LSTM ----------------
// grid barrier: epoch counting, agent scope. All threads fence their own
// stores to device scope, then thread 0 release-adds and acquire-spins.
__device__ __forceinline__ void gbar(unsigned* cnt, unsigned& epoch, int nblk) {
  __threadfence();
  __syncthreads();
  if (threadIdx.x == 0) {
    __hip_atomic_fetch_add(cnt, 1u, __ATOMIC_ACQ_REL, __HIP_MEMORY_SCOPE_AGENT);
    epoch += (unsigned)nblk;
    while (__hip_atomic_load(cnt, __ATOMIC_RELAXED, __HIP_MEMORY_SCOPE_AGENT) < epoch)
      __builtin_amdgcn_s_sleep(8);
    (void)__hip_atomic_load(cnt, __ATOMIC_ACQUIRE, __HIP_MEMORY_SCOPE_AGENT);
  }
  __syncthreads();
}

// All 16 LSTM steps in one kernel. 256 blocks (deadlock-safe: <= #CUs).
// XCD-aware decode (dispatch round-robins bid%8 across XCDs): XCD x owns
// n-pairs {2x, 2x+1} for ALL 16 m-tiles -> each XCD's weight slice
// (256 cols of whh1i + wc2i = 768 KB) stays L2-resident across all steps.
// BK=64, 2-phase prefetch, source-swizzled staging (chunk sp ^ (row&7)) so
// ds_read_b128 frag reads are ~conflict-free. Gate-interleaved weights
// (col n = 4*unit+gate, order i,f,g,o); acc initialized from P1/bsum2 (C-in);
// 3x shfl_xor butterfly; lanes with n%4==0 update c and write h.
__global__ __launch_bounds__(256, 2)
void lstm_k(const f16* __restrict__ P1, const f16* __restrict__ whh1i,
            const f16* __restrict__ wc2i, const float* __restrict__ bsum2,
            float* __restrict__ c1, float* __restrict__ c2,
            f16* __restrict__ h1a, f16* __restrict__ h1b,
            f16* __restrict__ h2a, f16* __restrict__ h2b,
            f16* __restrict__ hall, unsigned* __restrict__ bar)
{
  __shared__ f16 As[2][64][64];
  __shared__ f16 Bs[2][2][64][64];
  const int bid = blockIdx.x;
  const int xcd = bid & 7;
  const int idx = bid >> 3;            // 0..31
  const int bm = (idx >> 1) * 64;      // 16 m-tiles
  const int bn0 = (xcd * 2 + (idx & 1)) * 128;  // XCD-local n-pair
  const int tid = threadIdx.x;
  const int lane = tid & 63;
  const int wid = tid >> 6;
  const int l15 = lane & 15;
  const int l4 = lane >> 4;
  const int sr0 = tid >> 3;   // stage row 0..31 (+32 round 1)
  const int sp = tid & 7;     // stage chunk slot
  unsigned epoch = 0;

  // lane-constant swizzled frag-read byte offsets (within a 64x64 f16 tile)
  int offA[4][2], offB[2];
#pragma unroll
  for (int i = 0; i < 4; ++i)
#pragma unroll
    for (int h = 0; h < 2; ++h)
      offA[i][h] = (16 * i + l15) * 128 + (((l4 + 4 * h) ^ (l15 & 7)) * 16);
#pragma unroll
  for (int h = 0; h < 2; ++h)
    offB[h] = (wid * 16 + l15) * 128 + (((l4 + 4 * h) ^ (l15 & 7)) * 16);

  const int nn[2] = {bn0 + wid * 16 + l15, bn0 + 64 + wid * 16 + l15};

  for (int t = 0; t < Tt; ++t) {
    const f16* h1p = (t & 1) ? h1b : h1a;
    f16* h1n = (t & 1) ? h1a : h1b;
    const f16* h2p = (t & 1) ? h2b : h2a;
    f16* h2n = (t & 1) ? h2a : h2b;

    // ---- phase 1: gates1 = h1p @ whh1i^T + P1[t] -> cell1 -> h1n, c1 ----
    {
      auto stage = [&](int buf, int k0) {
#pragma unroll
        for (int rnd = 0; rnd < 2; ++rnd) {
          const int r = sr0 + 32 * rnd;
          const int gc = (sp ^ (r & 7)) * 16;
          gld16((char*)&As[buf][0][0] + rnd * 4096 + tid * 16,
                (const char*)h1p + ((size_t)(bm + r) * 512 + k0) * 2 + gc);
          gld16((char*)&Bs[buf][0][0][0] + rnd * 4096 + tid * 16,
                (const char*)whh1i + ((size_t)(bn0 + r) * 512 + k0) * 2 + gc);
          gld16((char*)&Bs[buf][1][0][0] + rnd * 4096 + tid * 16,
                (const char*)whh1i + ((size_t)(bn0 + 64 + r) * 512 + k0) * 2 + gc);
        }
      };
      // acc init = P1[t] (C-input); loads overlap the first stage+GEMM iters
      const f16* P1t = P1 + (size_t)t * 1024 * 2048;
      f32x4 acc[2][4];
#pragma unroll
      for (int j = 0; j < 2; ++j)
#pragma unroll
        for (int i = 0; i < 4; ++i) {
          const int row0 = bm + 16 * i + l4 * 4;
#pragma unroll
          for (int r = 0; r < 4; ++r)
            acc[j][i][r] = (float)P1t[(size_t)(row0 + r) * 2048 + nn[j]];
        }
      stage(0, 0);
      __syncthreads();
      for (int it = 0; it < 8; ++it) {
        const int cur = it & 1;
        if (it + 1 < 8) stage(cur ^ 1, (it + 1) * 64);
        const char* la = (const char*)&As[cur][0][0];
#pragma unroll
        for (int h = 0; h < 2; ++h) {
          f16x8 af[4];
#pragma unroll
          for (int i = 0; i < 4; ++i) af[i] = *(const f16x8*)(la + offA[i][h]);
#pragma unroll
          for (int j = 0; j < 2; ++j) {
            const f16x8 bf = *(const f16x8*)((const char*)&Bs[cur][j][0][0] + offB[h]);
#pragma unroll
            for (int i = 0; i < 4; ++i)
              acc[j][i] = __builtin_amdgcn_mfma_f32_16x16x32_f16(af[i], bf, acc[j][i], 0, 0, 0);
          }
        }
        __syncthreads();
      }
#pragma unroll
      for (int j = 0; j < 2; ++j) {
        const int n = nn[j];
        const int g0 = n & 3, jj = n >> 2;
#pragma unroll
        for (int i = 0; i < 4; ++i) {
          const int row0 = bm + 16 * i + l4 * 4;
#pragma unroll
          for (int r = 0; r < 4; ++r) {
            float v = acc[j][i][r];
            const float a1 = __shfl_xor(v, 1);
            const float a2 = __shfl_xor(v, 2);
            const float a3 = __shfl_xor(v, 3);
            if (g0 == 0) {
              const size_t ci = (size_t)(row0 + r) * 512 + jj;
              const float cv = fsig(a1) * c1[ci] + fsig(v) * ftanhf(a2);
              const float h = fsig(a3) * ftanhf(cv);
              c1[ci] = cv;
              h1n[ci] = (f16)h;
            }
          }
        }
      }
    }
    gbar(bar, epoch, 256);

    // ---- phase 2: gates2 = [h1n | h2p] @ wc2i^T + bsum2 -> cell2 ----
    {
      auto stage = [&](int buf, int k0) {
#pragma unroll
        for (int rnd = 0; rnd < 2; ++rnd) {
          const int r = sr0 + 32 * rnd;
          const int gc = (sp ^ (r & 7)) * 16;
          const char* asrc = (k0 < 512)
              ? (const char*)h1n + ((size_t)(bm + r) * 512 + k0) * 2
              : (const char*)h2p + ((size_t)(bm + r) * 512 + (k0 - 512)) * 2;
          gld16((char*)&As[buf][0][0] + rnd * 4096 + tid * 16, asrc + gc);
          gld16((char*)&Bs[buf][0][0][0] + rnd * 4096 + tid * 16,
                (const char*)wc2i + ((size_t)(bn0 + r) * 1024 + k0) * 2 + gc);
          gld16((char*)&Bs[buf][1][0][0] + rnd * 4096 + tid * 16,
                (const char*)wc2i + ((size_t)(bn0 + 64 + r) * 1024 + k0) * 2 + gc);
        }
      };
      f32x4 acc[2][4];
#pragma unroll
      for (int j = 0; j < 2; ++j) {
        const float bv = bsum2[nn[j]];
#pragma unroll
        for (int i = 0; i < 4; ++i)
#pragma unroll
          for (int r = 0; r < 4; ++r) acc[j][i][r] = bv;
      }
      stage(0, 0);
      __syncthreads();
      for (int it = 0; it < 16; ++it) {
        const int cur = it & 1;
        if (it + 1 < 16) stage(cur ^ 1, (it + 1) * 64);
        const char* la = (const char*)&As[cur][0][0];
#pragma unroll
        for (int h = 0; h < 2; ++h) {
          f16x8 af[4];
#pragma unroll
          for (int i = 0; i < 4; ++i) af[i] = *(const f16x8*)(la + offA[i][h]);
#pragma unroll
          for (int j = 0; j < 2; ++j) {
            const f16x8 bf = *(const f16x8*)((const char*)&Bs[cur][j][0][0] + offB[h]);
#pragma unroll
            for (int i = 0; i < 4; ++i)
              acc[j][i] = __builtin_amdgcn_mfma_f32_16x16x32_f16(af[i], bf, acc[j][i], 0, 0, 0);
          }
        }
        __syncthreads();
      }
#pragma unroll
      for (int j = 0; j < 2; ++j) {
        const int n = nn[j];
        const int g0 = n & 3, jj = n >> 2;
#pragma unroll
        for (int i = 0; i < 4; ++i) {
          const int row0 = bm + 16 * i + l4 * 4;
#pragma unroll
          for (int r = 0; r < 4; ++r) {
            float v = acc[j][i][r];
            const float a1 = __shfl_xor(v, 1);
            const float a2 = __shfl_xor(v, 2);
            const float a3 = __shfl_xor(v, 3);
            if (g0 == 0) {
              const size_t ci = (size_t)(row0 + r) * 512 + jj;
              const float cv = fsig(a1) * c2[ci] + fsig(v) * ftanhf(a2);
              const float h = fsig(a3) * ftanhf(cv);
              c2[ci] = cv;
              h2n[ci] = (f16)h;
              hall[((size_t)t * 1024 + row0 + r) * 512 + jj] = (f16)h;
            }
          }
        }
      }
    }
    gbar(bar, epoch, 256);
  }
}

// ---------------- elementwise / reductions ----------------

__device__ __forceinline__ double block_reduce_d(double v) {
  __shared__ double sred[4];
#pragma unroll
  for (int off = 32; off > 0; off >>= 1) v += __shfl_down(v, off);
  const int lane = threadIdx.x & 63;
  const int w = threadIdx.x >> 6;
  if (lane == 0) sred[w] = v;
  __syncthreads();
  double r = 0.0;
  if (threadIdx.x == 0) {
    const int nw = blockDim.x >> 6;
    r = sred[0];
    for (int i = 1; i < nw; ++i) r += sred[i];
  }
  return r;
}

// z fp32; inp384 = [z_active(128) | p(256)] for layer 8 (even k); inp512 p-half
__global__ __launch_bounds__(256)
void split_k(const float* __restrict__ nf, float* __restrict__ z,
             f16* __restrict__ inp384, f16* __restrict__ inp512) {
  const int n = BT * Zd;
  for (int i = blockIdx.x * blockDim.x + threadIdx.x; i < n; i += gridDim.x * blockDim.x) {
    const int m = i >> 8, k = i & 255;
    const float pv = nf[(size_t)m * 512 + k];
    const float zv = nf[(size_t)m * 512 + 256 + k];
    z[(size_t)m * 256 + k] = zv;
    inp512[(size_t)m * 512 + 256 + k] = (f16)pv;
    inp384[(size_t)m * 384 + 128 + k] = (f16)pv;
    if ((k & 1) == 0) inp384[(size_t)m * 384 + (k >> 1)] = (f16)zv;  // layer 8: even kept
  }
}

// one wave per row (4 rows/block). LAST=0: z update + ldj + compact next z-half.
// LAST=1 (layer 0): final update -> out[1..], logN(z3) into acc[1], xbuf slabs.
template <int LAST>
__global__ __launch_bounds__(256)
void flow_update_k(float* __restrict__ z, const f16* __restrict__ s16,
                   const f16* __restrict__ t16, float* __restrict__ ldj,
                   f16* __restrict__ inp384, int layer, int nextlayer,
                   float* __restrict__ out, f16* __restrict__ xbuf,
                   double* __restrict__ acc) {
  const int w = threadIdx.x >> 6, lane = threadIdx.x & 63;
  const int m = blockIdx.x * 4 + w;
  const int k0 = lane * 4;
  const size_t base = (size_t)m * 256 + k0;
  const float4 zv = *(const float4*)(z + base);
  const f16x4 sv = *(const f16x4*)(s16 + base);
  const f16x4 tv = *(const f16x4*)(t16 + base);
  float zr[4] = {zv.x, zv.y, zv.z, zv.w};
  float ssum = 0.f;
  float zn[4];
#pragma unroll
  for (int e = 0; e < 4; ++e) {
    const float s = (float)sv[e];
    ssum += s;
    zn[e] = maskbit(layer, k0 + e) ? zr[e] : (zr[e] - (float)tv[e]) * __expf(-s);
  }
  if (!LAST) {
    *(float4*)(z + base) = make_float4(zn[0], zn[1], zn[2], zn[3]);
    if (nextlayer > 0) {
      const int par = nextlayer & 1;  // odd layer keeps odd k
      f16x2 o;
      o[0] = (f16)zn[par];
      o[1] = (f16)zn[par + 2];
      *(f16x2*)(inp384 + (size_t)m * 384 + (k0 >> 1)) = o;
    }
  } else {
    // out (offset 1, scalar stores), xbuf slab t+1, logN accumulation
#pragma unroll
    for (int e = 0; e < 4; ++e) out[1 + base + e] = zn[e];
    const int b = m >> 4, tt = m & 15;
    if (tt < 15) {
      f16x4 xo;
#pragma unroll
      for (int e = 0; e < 4; ++e) xo[e] = (f16)zn[e];
      *(f16x4*)(xbuf + (((size_t)(tt + 1) << 10) + b) * 256 + k0) = xo;
    }
    double ln = 0.0;
#pragma unroll
    for (int e = 0; e < 4; ++e)
      ln += (double)(-0.5f * zn[e] * zn[e] - LOG_SQRT_2PI_F);
#pragma unroll
    for (int off = 32; off > 0; off >>= 1) ln += __shfl_down(ln, off);
    __shared__ double lred[4];
    if (lane == 0) lred[w] = ln;
    __syncthreads();
    if (threadIdx.x == 0)
      atomicAdd(acc + 1, lred[0] + lred[1] + lred[2] + lred[3]);
  }
#pragma unroll
  for (int off = 32; off > 0; off >>= 1) ssum += __shfl_down(ssum, off);
  if (lane == 0) ldj[m] -= ssum;
}

// layer-0 input: z_shift into inp512 z-half
__global__ __launch_bounds__(256)
void prep0_k(const float* __restrict__ z, f16* __restrict__ inp512) {
  const int n = BT * Zd;
  for (int i = blockIdx.x * blockDim.x + threadIdx.x; i < n; i += gridDim.x * blockDim.x) {
    const int m = i >> 8, k = i & 255;
    const float v = ((m & 15) == 0) ? 0.f : z[(size_t)(m - 1) * 256 + k];
    inp512[(size_t)m * 512 + k] = (f16)v;
  }
}

__global__ __launch_bounds__(256)
void ldj_sum_k(const float* __restrict__ ldj, double* __restrict__ acc) {
  double local = 0.0;
  for (int i = blockIdx.x * blockDim.x + threadIdx.x; i < BT; i += gridDim.x * blockDim.x)
    local += (double)ldj[i];
  local = block_reduce_d(local);
  if (threadIdx.x == 0) atomicAdd(acc + 1, local);
}

// z3 read from out[1..]
__global__ __launch_bounds__(256)
void post_all_k(const f16* __restrict__ mv, const float* __restrict__ out,
                double* __restrict__ acc) {
  const int n = BT * Zd;
  double local = 0.0;
  for (int i = blockIdx.x * blockDim.x + threadIdx.x; i < n; i += gridDim.x * blockDim.x) {
    const int k = i & 255;
    const int row = i >> 8;               // t*1024 + b
    const int t = row >> 10, b = row & 1023;
    const float mean = (float)mv[(size_t)row * 512 + k];
    const float lv = (float)mv[(size_t)row * 512 + 256 + k];
    const float zv = out[1 + ((size_t)b * 16 + t) * 256 + k];
    const float d = (zv - mean) * __expf(-lv);
    local += (double)(-0.5f * d * d - LOG_SQRT_2PI_F) - (double)lv;
  }
  local = block_reduce_d(local);
  if (threadIdx.x == 0) atomicAdd(acc + 0, local);
}

__global__ void finalize_k(const double* __restrict__ acc, float* __restrict__ out) {
  const double loglik = 0.0025 * acc[0] + acc[1];
  out[0] = (float)(-loglik / (double)Bb);
}

// ---------------- weight conversion ----------------
__global__ __launch_bounds__(256)
void cvt_k(const float* __restrict__ s, f16* __restrict__ d, int n) {
  for (int i = blockIdx.x * blockDim.x + threadIdx.x; i < n; i += gridDim.x * blockDim.x)
    d[i] = (f16)s[i];
}

__global__ __launch_bounds__(256)
void cvt_cat_rows_k(const float* __restrict__ a, const float* __restrict__ b,
                    f16* __restrict__ d, int L, int R, int K) {
  const int n = L * 2 * R * K;
  for (int i = blockIdx.x * blockDim.x + threadIdx.x; i < n; i += gridDim.x * blockDim.x) {
    const int k = i % K;
    const int rem = i / K;
    const int r = rem % (2 * R);
    const int l = rem / (2 * R);
    const float v = (r < R) ? a[((size_t)l * R + r) * K + k]
                            : b[((size_t)l * R + (r - R)) * K + k];
    d[i] = (f16)v;
  }
}

// w1a[1024][512] (layer 0 full) + w1b[8][1024][384] (layers 1..8, z-cols gathered)
__global__ __launch_bounds__(256)
void cvt_w1_k(const float* __restrict__ sW1, const float* __restrict__ tW1,
              f16* __restrict__ w1a, f16* __restrict__ w1b) {
  const int N0 = 1024 * 512;
  const int N1 = 8 * 1024 * 384;
  for (int i = blockIdx.x * blockDim.x + threadIdx.x; i < N0 + N1; i += gridDim.x * blockDim.x) {
    if (i < N0) {
      const int r = i / 512, k = i % 512;
      const float* S = (r < 512) ? sW1 : tW1;
      w1a[i] = (f16)S[(size_t)(r & 511) * 512 + k];
    } else {
      const int jj = i - N0;
      const int k = jj % 384;
      const int r = (jj / 384) & 1023;
      const int l = jj / (384 * 1024) + 1;
      const int col = (k < 128) ? (2 * k + (l & 1)) : (k + 128);
      const float* S = (r < 512) ? sW1 : tW1;
      w1b[jj] = (f16)S[((size_t)l * 512 + (r & 511)) * 512 + col];
    }
  }
}

// gate-interleaved fp16: d[n][k], K=ka+kb, old row = (n&3)*512 + (n>>2)
__global__ __launch_bounds__(256)
void cvt_int_k(const float* __restrict__ a, int ka, const float* __restrict__ b,
               int kb, f16* __restrict__ d, int N) {
  const int K = ka + kb;
  const int n_tot = N * K;
  for (int i = blockIdx.x * blockDim.x + threadIdx.x; i < n_tot; i += gridDim.x * blockDim.x) {
    const int k = i % K;
    const int n = i / K;
    const int row = (n & 3) * 512 + (n >> 2);
    const float v = (k < ka) ? a[(size_t)row * ka + k] : b[(size_t)row * kb + (k - ka)];
    d[i] = (f16)v;
  }
}

__global__ __launch_bounds__(256)
void bsum_int_k(const float* __restrict__ bih, const float* __restrict__ bhh,
                float* __restrict__ d) {
  const int i = blockIdx.x * blockDim.x + threadIdx.x;
  if (i < 2048) {
    const int row = (i & 3) * 512 + (i >> 2);
    d[i] = bih[row] + bhh[row];
  }
}

__global__ __launch_bounds__(256)
void fcat_k(const float* __restrict__ a, const float* __restrict__ b,
            float* __restrict__ d, int L, int R) {
  const int n = L * 2 * R;
  for (int i = blockIdx.x * blockDim.x + threadIdx.x; i < n; i += gridDim.x * blockDim.x) {
    const int c = i % (2 * R);
    const int l = i / (2 * R);
    d[i] = (c < R) ? a[(size_t)l * R + c] : b[(size_t)l * R + (c - R)];
  }
}

// ---------------- host launch ----------------
extern "C" void kernel_launch(void* const* d_in, const int* in_sizes, int n_in,
                              void* d_out, int out_size, void* d_ws, size_t ws_size,
                              hipStream_t stream) {
  (void)in_sizes; (void)n_in; (void)out_size; (void)ws_size;

  const float* nf    = (const float*)d_in[0];
  const float* sW1   = (const float*)d_in[1];
  const float* sb1   = (const float*)d_in[2];
  const float* sW2   = (const float*)d_in[3];
  const float* sb2   = (const float*)d_in[4];
  const float* sW3   = (const float*)d_in[5];
  const float* sb3   = (const float*)d_in[6];
  const float* tW1   = (const float*)d_in[7];
  const float* tb1   = (const float*)d_in[8];
  const float* tW2   = (const float*)d_in[9];
  const float* tb2   = (const float*)d_in[10];
  const float* tW3   = (const float*)d_in[11];
  const float* tb3   = (const float*)d_in[12];
  const float* l1Wih = (const float*)d_in[13];
  const float* l1Whh = (const float*)d_in[14];
  const float* l1bih = (const float*)d_in[15];
  const float* l1bhh = (const float*)d_in[16];
  const float* l2Wih = (const float*)d_in[17];
  const float* l2Whh = (const float*)d_in[18];
  const float* l2bih = (const float*)d_in[19];
  const float* l2bhh = (const float*)d_in[20];
  const float* mW    = (const float*)d_in[21];
  const float* mb    = (const float*)d_in[22];
  const float* lvW   = (const float*)d_in[23];
  const float* lvb   = (const float*)d_in[24];

  float* out = (float*)d_out;

  char* wsb = (char*)d_ws;
  size_t off = 0;
  auto alloc = [&](size_t bytes) -> char* {
    char* p = wsb + off;
    off += (bytes + 255) & ~(size_t)255;
    return p;
  };
  double*   acc    = (double*)alloc(32);          // acc[0], acc[1], bar
  unsigned* bar    = (unsigned*)(acc + 2);
  float*  z      = (float*)alloc((size_t)BT * Zd * 4);
  f16*    inp512 = (f16*)alloc((size_t)BT * 512 * 2);   // LSTM: mvbuf
  f16*    inp384 = (f16*)alloc((size_t)BT * 384 * 2);   // LSTM: xbuf (first 8MB)
  f16*    hidA   = (f16*)alloc((size_t)BT * 1024 * 2);  // LSTM: P1 (spans hidA+hidB)
  f16*    hidB   = (f16*)alloc((size_t)BT * 1024 * 2);
  f16*    s16b   = (f16*)alloc((size_t)BT * Zd * 2);    // LSTM: h1a,h1b,h2a,h2b
  f16*    t16b   = (f16*)alloc((size_t)BT * Zd * 2);    // LSTM: c1,c2 (fp32)
  f16*    hall   = (f16*)alloc((size_t)BT * 512 * 2);
  float*  ldj    = (float*)alloc((size_t)BT * 4);
  f16* w1a   = (f16*)alloc((size_t)1024 * 512 * 2);
  f16* w1b   = (f16*)alloc((size_t)8 * 1024 * 384 * 2);
  f16* w2s   = (f16*)alloc((size_t)9 * 512 * 512 * 2);
  f16* w2t   = (f16*)alloc((size_t)9 * 512 * 512 * 2);
  f16* w3s   = (f16*)alloc((size_t)9 * 256 * 512 * 2);
  f16* w3t   = (f16*)alloc((size_t)9 * 256 * 512 * 2);
  f16* wih1i = (f16*)alloc((size_t)2048 * 256 * 2);
  f16* whh1i = (f16*)alloc((size_t)2048 * 512 * 2);
  f16* wc2i  = (f16*)alloc((size_t)2048 * 1024 * 2);
  f16* wmv   = (f16*)alloc((size_t)512 * 512 * 2);
  float* bcat1 = (float*)alloc((size_t)9 * 1024 * 4);
  float* bsum1 = (float*)alloc((size_t)2048 * 4);
  float* bsum2 = (float*)alloc((size_t)2048 * 4);
  float* bmv   = (float*)alloc((size_t)512 * 4);

  // LSTM-phase aliases
  f16*   xbuf  = inp384;                                 // [16][1024][256]
  f16*   P1    = hidA;                                   // [16384][2048]
  f16*   h1a   = s16b;                                   // 4 x [1024][512] f16
  f16*   h1b   = h1a + (size_t)1024 * 512;
  f16*   h2a   = h1b + (size_t)1024 * 512;
  f16*   h2b   = h2a + (size_t)1024 * 512;
  float* c1    = (float*)t16b;                           // 2 x [1024][512] fp32
  float* c2    = c1 + (size_t)1024 * 512;
  f16*   mvbuf = inp512;                                 // [16384][512]

  // ---- weight conversions ----
  cvt_w1_k<<<2048, 256, 0, stream>>>(sW1, tW1, w1a, w1b);
  cvt_k<<<2048, 256, 0, stream>>>(sW2, w2s, 9 * 512 * 512);
  cvt_k<<<2048, 256, 0, stream>>>(tW2, w2t, 9 * 512 * 512);
  cvt_k<<<1024, 256, 0, stream>>>(sW3, w3s, 9 * 256 * 512);
  cvt_k<<<1024, 256, 0, stream>>>(tW3, w3t, 9 * 256 * 512);
  cvt_int_k<<<1024, 256, 0, stream>>>(l1Wih, 256, l1Wih, 0, wih1i, 2048);
  cvt_int_k<<<1024, 256, 0, stream>>>(l1Whh, 512, l1Whh, 0, whh1i, 2048);
  cvt_int_k<<<1024, 256, 0, stream>>>(l2Wih, 512, l2Whh, 512, wc2i, 2048);
  cvt_cat_rows_k<<<256, 256, 0, stream>>>(mW, lvW, wmv, 1, 256, 512);
  fcat_k<<<16, 256, 0, stream>>>(sb1, tb1, bcat1, 9, 512);
  bsum_int_k<<<8, 256, 0, stream>>>(l1bih, l1bhh, bsum1);
  bsum_int_k<<<8, 256, 0, stream>>>(l2bih, l2bhh, bsum2);
  fcat_k<<<2, 256, 0, stream>>>(mb, lvb, bmv, 1, 256);

  hipMemsetAsync(acc, 0, 32, stream);   // acc + bar
  hipMemsetAsync(ldj, 0, (size_t)BT * 4, stream);

  split_k<<<2048, 256, 0, stream>>>(nf, z, inp384, inp512);

  // ---- inverse flow: layers 8..0 ----
  for (int i = NL - 1; i >= 0; --i) {
    if (i == 0)
      hgemm2_k<EPI_LEAKY, EPI_LEAKY><<<dim3(128, 8, 1), 256, 0, stream>>>(
          inp512, inp512, 512, w1a, w1a, 512, 512, bcat1, bcat1, hidA, hidA, 1024, 0);
    else
      hgemm2_k<EPI_LEAKY, EPI_LEAKY><<<dim3(128, 8, 1), 256, 0, stream>>>(
          inp384, inp384, 384, w1b + (size_t)(i - 1) * 1024 * 384,
          w1b + (size_t)(i - 1) * 1024 * 384, 384, 384,
          bcat1 + i * 1024, bcat1 + i * 1024, hidA, hidA, 1024, 0);
    hgemm2_k<EPI_LEAKY, EPI_LEAKY><<<dim3(128, 4, 2), 256, 0, stream>>>(
        hidA, hidA + 512, 1024, w2s + (size_t)i * 512 * 512, w2t + (size_t)i * 512 * 512,
        512, 512, sb2 + i * 512, tb2 + i * 512, hidB, hidB + 512, 1024, 0);
    hgemm2_k<EPI_S, EPI_T><<<dim3(128, 2, 2), 256, 0, stream>>>(
        hidB, hidB + 512, 1024, w3s + (size_t)i * 256 * 512, w3t + (size_t)i * 256 * 512,
        512, 512, sb3 + i * 256, tb3 + i * 256, s16b, t16b, 256, i);
    if (i > 0) {
      flow_update_k<0><<<BT / 4, 256, 0, stream>>>(
          z, s16b, t16b, ldj, inp384, i, i - 1, nullptr, nullptr, nullptr);
      if (i - 1 == 0) prep0_k<<<2048, 256, 0, stream>>>(z, inp512);
    } else {
      flow_update_k<1><<<BT / 4, 256, 0, stream>>>(
          z, s16b, t16b, ldj, nullptr, 0, -1, out, xbuf, acc);
    }
  }

  ldj_sum_k<<<64, 256, 0, stream>>>(ldj, acc);

  // ---- LSTM prior ----
  hipMemsetAsync(h1a, 0, (size_t)4 * 1024 * 512 * 2, stream);   // h1a,h1b,h2a,h2b
  hipMemsetAsync(c1, 0, (size_t)2 * 1024 * 512 * 4, stream);    // c1,c2
  hipMemsetAsync(xbuf, 0, (size_t)1024 * 256 * 2, stream);      // t=0 slab
  hgemm2_k<EPI_MV, EPI_MV><<<dim3(128, 16, 1), 256, 0, stream>>>(
      xbuf, xbuf, 256, wih1i, wih1i, 256, 256, bsum1, bsum1, P1, P1, 2048, 0);
  lstm_k<<<256, 256, 0, stream>>>(P1, whh1i, wc2i, bsum2, c1, c2,
                                  h1a, h1b, h2a, h2b, hall, bar);

  hgemm2_k<EPI_MV, EPI_MV><<<dim3(128, 4, 1), 256, 0, stream>>>(
      hall, hall, 512, wmv, wmv, 512, 512, bmv, bmv, mvbuf, mvbuf, 512, 0);
  post_all_k<<<1024, 256, 0, stream>>>(mvbuf, out, acc);

  finalize_k<<<1, 1, 0, stream>>>(acc, out);
}

// Round 10
// 1459.321 us; speedup vs baseline: 2.8593x; 2.5621x over previous
//
#include <hip/hip_runtime.h>
#include <math.h>

// ---------------- problem constants ----------------
constexpr int Zd = 256, Tt = 16, NF = 512, Hh = 512, NL = 9, Bb = 1024;
constexpr int BT = Bb * Tt; // 16384
constexpr float LOG_SQRT_2PI_F = 0.9189385332046727f;

typedef _Float16 f16;
typedef __attribute__((ext_vector_type(4))) _Float16 f16x4;
typedef __attribute__((ext_vector_type(8))) _Float16 f16x8;
typedef __attribute__((ext_vector_type(4))) float f32x4;

__device__ __forceinline__ bool maskbit(int layer, int k) {
  if (layer == 0) return false;
  return (layer & 1) ? ((k & 1) != 0) : ((k & 1) == 0);
}

__device__ __forceinline__ void gld16(void* lds, const void* g) {
  __builtin_amdgcn_global_load_lds(
      (const __attribute__((address_space(1))) void*)g,
      (__attribute__((address_space(3))) void*)lds, 16, 0, 0);
}

__device__ __forceinline__ float fsig(float x) {
  return __builtin_amdgcn_rcpf(1.f + __expf(-x));
}
__device__ __forceinline__ float ftanhf(float x) {
  const float e = __expf(2.f * x);
  return 1.f - 2.f * __builtin_amdgcn_rcpf(e + 1.f);
}

enum { EPI_LEAKY = 0, EPI_S = 1, EPI_T = 2, EPI_MV = 3 };

template <int EPI>
__device__ __forceinline__ void epilogue128(const f32x4 (&acc)[4][4],
                                            const float* __restrict__ bias,
                                            void* __restrict__ C0, int ldc,
                                            int layer, int bm, int bn, int wr,
                                            int wc, int l15, int l4) {
#pragma unroll
  for (int i = 0; i < 4; ++i) {
    const int row0 = bm + wr + 16 * i + l4 * 4;
#pragma unroll
    for (int j = 0; j < 4; ++j) {
      const int col = bn + wc + 16 * j + l15;
#pragma unroll
      for (int r = 0; r < 4; ++r) {
        float v = acc[i][j][r];
        const size_t ci = (size_t)(row0 + r) * ldc + col;
        if (EPI == EPI_LEAKY) {
          v += bias[col];
          v = v > 0.f ? v : 0.01f * v;
          ((f16*)C0)[ci] = (f16)v;
        } else if (EPI == EPI_S) {
          v = ftanhf(v + bias[col]);
          if (maskbit(layer, col)) v = 0.f;
          ((f16*)C0)[ci] = (f16)v;
        } else if (EPI == EPI_T) {
          v += bias[col];
          if (maskbit(layer, col)) v = 0.f;
          ((f16*)C0)[ci] = (f16)v;
        } else { // EPI_MV
          ((f16*)C0)[ci] = (f16)(v + bias[col]);
        }
      }
    }
  }
}

// Dual GEMM: blockIdx.z selects parameter set. C = epi(A[M,K(lda)] @ W[N,K(ldw)]^T)
// 128x128 tile, BK=32, 4 waves, 2-phase prefetch double-buffered LDS.
template <int EPI0, int EPI1>
__global__ __launch_bounds__(256, 4)
void hgemm2_k(const f16* __restrict__ A0, const f16* __restrict__ A1, int lda,
              const f16* __restrict__ W0, const f16* __restrict__ W1, int K, int ldw,
              const float* __restrict__ b0, const float* __restrict__ b1,
              void* __restrict__ C0v, void* __restrict__ C1v, int ldc, int layer)
{
  __shared__ f16 As[2][128][32];
  __shared__ f16 Bs[2][128][32];
  const int zsel = blockIdx.z;
  const f16* A = zsel ? A1 : A0;
  const f16* W = zsel ? W1 : W0;
  const float* bias = zsel ? b1 : b0;
  void* Cv = zsel ? C1v : C0v;

  const int bm = blockIdx.x * 128;
  const int bn = blockIdx.y * 128;
  const int tid = threadIdx.x;
  const int lane = tid & 63;
  const int wid = tid >> 6;
  const int wr = (wid >> 1) * 64;
  const int wc = (wid & 1) * 64;
  const int l15 = lane & 15;
  const int l4 = lane >> 4;
  const int arow = tid >> 2;
  const int akb = (tid & 3) * 16;

  const char* Ab = (const char*)A + (size_t)(bm + arow) * lda * 2 + akb;
  const char* Wb = (const char*)W + (size_t)(bn + arow) * ldw * 2 + akb;

  auto stage = [&](int buf, int k0) {
    const size_t kb = (size_t)k0 * 2;
    char* la = (char*)&As[buf][0][0];
    char* lb = (char*)&Bs[buf][0][0];
    gld16(la + tid * 16, Ab + kb);
    gld16(la + 4096 + tid * 16, Ab + kb + (size_t)lda * 128);
    gld16(lb + tid * 16, Wb + kb);
    gld16(lb + 4096 + tid * 16, Wb + kb + (size_t)ldw * 128);
  };

  f32x4 acc[4][4] = {};
  const int nk = K >> 5;
  stage(0, 0);
  __syncthreads();

  for (int t = 0; t < nk; ++t) {
    const int cur = t & 1;
    if (t + 1 < nk) stage(cur ^ 1, (t + 1) << 5);
    f16x8 af[4], bf[4];
#pragma unroll
    for (int i = 0; i < 4; ++i) af[i] = *(const f16x8*)&As[cur][wr + 16 * i + l15][l4 * 8];
#pragma unroll
    for (int j = 0; j < 4; ++j) bf[j] = *(const f16x8*)&Bs[cur][wc + 16 * j + l15][l4 * 8];
#pragma unroll
    for (int i = 0; i < 4; ++i)
#pragma unroll
      for (int j = 0; j < 4; ++j)
        acc[i][j] = __builtin_amdgcn_mfma_f32_16x16x32_f16(af[i], bf[j], acc[i][j], 0, 0, 0);
    __syncthreads();
  }

  if (zsel == 0)
    epilogue128<EPI0>(acc, bias, Cv, ldc, layer, bm, bn, wr, wc, l15, l4);
  else
    epilogue128<EPI1>(acc, bias, Cv, ldc, layer, bm, bn, wr, wc, l15, l4);
}

// ---------------- paired LSTM gate GEMM + fused cell ----------------
// blockIdx.z==0: layer2[t]:  gates2 = [h1cur | h2prev] @ wc2i^T + bsum2 (K=1024)
//                -> cell2 -> c2, h2next, hallt
// blockIdx.z==1: layer1[t+1]: gates1 = [xnext | h1cur] @ wc1i^T + bsum1 (K=768)
//                -> cell1 -> c1, h1next
// Both depend only on h1cur (written by the PREVIOUS dispatch) -> 16 sequential
// dispatches instead of 32. 64x64 tile, BK=32, 2-phase prefetch.
// Gate-interleaved weights (col n = 4*unit+gate, order i,f,g,o); 3x shfl_xor
// butterfly; lanes with n%4==0 update c and write h.
__global__ __launch_bounds__(256, 4)
void pairgate_k(const f16* __restrict__ xnext, const f16* __restrict__ h1cur,
                const f16* __restrict__ h2prev,
                const f16* __restrict__ wc2i, const f16* __restrict__ wc1i,
                const float* __restrict__ bsum2, const float* __restrict__ bsum1,
                float* __restrict__ c1, float* __restrict__ c2,
                f16* __restrict__ h1next, f16* __restrict__ h2next,
                f16* __restrict__ hallt)
{
  __shared__ f16 As[2][64][32];
  __shared__ f16 Bs[2][64][32];
  const int zsel = blockIdx.z;
  const int K = zsel ? 768 : 1024;
  const f16* W = zsel ? wc1i : wc2i;
  const float* bsum = zsel ? bsum1 : bsum2;
  const int bm = blockIdx.x * 64;
  const int bn = blockIdx.y * 64;
  const int tid = threadIdx.x;
  const int lane = tid & 63;
  const int wid = tid >> 6;
  const int l15 = lane & 15;
  const int l4 = lane >> 4;
  const int lr = tid >> 2;
  const int lk = (tid & 3) * 16;

  auto stage = [&](int buf, int k0) {
    const char* asrc;
    if (zsel == 0) {
      asrc = (k0 < 512)
          ? (const char*)h1cur + ((size_t)(bm + lr) * 512 + k0) * 2
          : (const char*)h2prev + ((size_t)(bm + lr) * 512 + (k0 - 512)) * 2;
    } else {
      asrc = (k0 < 256)
          ? (const char*)xnext + ((size_t)(bm + lr) * 256 + k0) * 2
          : (const char*)h1cur + ((size_t)(bm + lr) * 512 + (k0 - 256)) * 2;
    }
    gld16((char*)&As[buf][0][0] + tid * 16, asrc + lk);
    gld16((char*)&Bs[buf][0][0] + tid * 16,
          (const char*)W + ((size_t)(bn + lr) * K + k0) * 2 + lk);
  };

  const int n = bn + wid * 16 + l15;
  f32x4 acc[4];
  {
    const float bv = bsum[n];
#pragma unroll
    for (int i = 0; i < 4; ++i)
#pragma unroll
      for (int r = 0; r < 4; ++r) acc[i][r] = bv;
  }

  const int nk = K >> 5;
  stage(0, 0);
  __syncthreads();

  for (int t = 0; t < nk; ++t) {
    const int cur = t & 1;
    if (t + 1 < nk) stage(cur ^ 1, (t + 1) << 5);
    f16x8 af[4], bf;
#pragma unroll
    for (int i = 0; i < 4; ++i) af[i] = *(const f16x8*)&As[cur][16 * i + l15][l4 * 8];
    bf = *(const f16x8*)&Bs[cur][wid * 16 + l15][l4 * 8];
#pragma unroll
    for (int i = 0; i < 4; ++i)
      acc[i] = __builtin_amdgcn_mfma_f32_16x16x32_f16(af[i], bf, acc[i], 0, 0, 0);
    __syncthreads();
  }

  float* cst = zsel ? c1 : c2;
  f16* hout = zsel ? h1next : h2next;
  const int g0 = n & 3, jj = n >> 2;
#pragma unroll
  for (int i = 0; i < 4; ++i) {
    const int row0 = bm + 16 * i + l4 * 4;
#pragma unroll
    for (int r = 0; r < 4; ++r) {
      const float v = acc[i][r];
      const float a1 = __shfl_xor(v, 1);
      const float a2 = __shfl_xor(v, 2);
      const float a3 = __shfl_xor(v, 3);
      if (g0 == 0) {  // v=i, a1=f, a2=g, a3=o
        const size_t ci = (size_t)(row0 + r) * 512 + jj;
        const float cv = fsig(a1) * cst[ci] + fsig(v) * ftanhf(a2);
        const float h = fsig(a3) * ftanhf(cv);
        cst[ci] = cv;
        hout[ci] = (f16)h;
        if (zsel == 0) hallt[ci] = (f16)h;
      }
    }
  }
}

// t=0 layer-1 cell: x=0, h=0 -> gates = bsum1 only. Per-unit analytic init.
__global__ __launch_bounds__(256)
void cell0_k(const float* __restrict__ bsum1, float* __restrict__ c1,
             f16* __restrict__ h1n0) {
  const int idx = blockIdx.x * 256 + threadIdx.x;  // < 1024*512
  const int j = idx & 511;
  const float gi = bsum1[4 * j], gf = bsum1[4 * j + 1];
  const float gg = bsum1[4 * j + 2], go = bsum1[4 * j + 3];
  (void)gf;
  const float cv = fsig(gi) * ftanhf(gg);
  c1[idx] = cv;
  h1n0[idx] = (f16)(fsig(go) * ftanhf(cv));
}

// ---------------- elementwise / reductions ----------------

__device__ __forceinline__ double block_reduce_d(double v) {
  __shared__ double sred[4];
#pragma unroll
  for (int off = 32; off > 0; off >>= 1) v += __shfl_down(v, off);
  const int lane = threadIdx.x & 63;
  const int w = threadIdx.x >> 6;
  if (lane == 0) sred[w] = v;
  __syncthreads();
  double r = 0.0;
  if (threadIdx.x == 0) {
    const int nw = blockDim.x >> 6;
    r = sred[0];
    for (int i = 1; i < nw; ++i) r += sred[i];
  }
  return r;
}

// z fp32, inp512 p-half, inp512 z-half masked for layer 8 (even k kept)
__global__ __launch_bounds__(256)
void split_k(const float* __restrict__ nf, float* __restrict__ z,
             f16* __restrict__ inp512) {
  const int n = BT * Zd;
  for (int i = blockIdx.x * blockDim.x + threadIdx.x; i < n; i += gridDim.x * blockDim.x) {
    const int m = i >> 8, k = i & 255;
    const float pv = nf[(size_t)m * 512 + k];
    const float zv = nf[(size_t)m * 512 + 256 + k];
    z[(size_t)m * 256 + k] = zv;
    inp512[(size_t)m * 512 + 256 + k] = (f16)pv;
    inp512[(size_t)m * 512 + k] = ((k & 1) == 0) ? (f16)zv : (f16)0.f;
  }
}

// one wave per row (4 rows/block). LAST=0: z update + ldj + next masked z-half.
// LAST=1 (layer 0): final update -> out[1..], logN(z3) into acc[1], xbuf slabs.
template <int LAST>
__global__ __launch_bounds__(256)
void flow_update_k(float* __restrict__ z, const f16* __restrict__ s16,
                   const f16* __restrict__ t16, float* __restrict__ ldj,
                   f16* __restrict__ inp512, int layer, int nextlayer,
                   float* __restrict__ out, f16* __restrict__ xbuf,
                   double* __restrict__ acc) {
  const int w = threadIdx.x >> 6, lane = threadIdx.x & 63;
  const int m = blockIdx.x * 4 + w;
  const int k0 = lane * 4;
  const size_t base = (size_t)m * 256 + k0;
  const float4 zv = *(const float4*)(z + base);
  const f16x4 sv = *(const f16x4*)(s16 + base);
  const f16x4 tv = *(const f16x4*)(t16 + base);
  float zr[4] = {zv.x, zv.y, zv.z, zv.w};
  float ssum = 0.f;
  float zn[4];
#pragma unroll
  for (int e = 0; e < 4; ++e) {
    const float s = (float)sv[e];
    ssum += s;
    zn[e] = maskbit(layer, k0 + e) ? zr[e] : (zr[e] - (float)tv[e]) * __expf(-s);
  }
  if (!LAST) {
    *(float4*)(z + base) = make_float4(zn[0], zn[1], zn[2], zn[3]);
    if (nextlayer > 0) {
      f16x4 o;
#pragma unroll
      for (int e = 0; e < 4; ++e)
        o[e] = maskbit(nextlayer, k0 + e) ? (f16)zn[e] : (f16)0.f;
      *(f16x4*)(inp512 + (size_t)m * 512 + k0) = o;
    }
  } else {
    // out (offset 1, scalar stores), xbuf slab t+1, logN accumulation
#pragma unroll
    for (int e = 0; e < 4; ++e) out[1 + base + e] = zn[e];
    const int b = m >> 4, tt = m & 15;
    if (tt < 15) {
      f16x4 xo;
#pragma unroll
      for (int e = 0; e < 4; ++e) xo[e] = (f16)zn[e];
      *(f16x4*)(xbuf + (((size_t)(tt + 1) << 10) + b) * 256 + k0) = xo;
    }
    double ln = 0.0;
#pragma unroll
    for (int e = 0; e < 4; ++e)
      ln += (double)(-0.5f * zn[e] * zn[e] - LOG_SQRT_2PI_F);
#pragma unroll
    for (int off = 32; off > 0; off >>= 1) ln += __shfl_down(ln, off);
    __shared__ double lred[4];
    if (lane == 0) lred[w] = ln;
    __syncthreads();
    if (threadIdx.x == 0)
      atomicAdd(acc + 1, lred[0] + lred[1] + lred[2] + lred[3]);
  }
#pragma unroll
  for (int off = 32; off > 0; off >>= 1) ssum += __shfl_down(ssum, off);
  if (lane == 0) ldj[m] -= ssum;
}

// layer-0 input: z_shift into inp512 z-half
__global__ __launch_bounds__(256)
void prep0_k(const float* __restrict__ z, f16* __restrict__ inp512) {
  const int n = BT * Zd;
  for (int i = blockIdx.x * blockDim.x + threadIdx.x; i < n; i += gridDim.x * blockDim.x) {
    const int m = i >> 8, k = i & 255;
    const float v = ((m & 15) == 0) ? 0.f : z[(size_t)(m - 1) * 256 + k];
    inp512[(size_t)m * 512 + k] = (f16)v;
  }
}

__global__ __launch_bounds__(256)
void ldj_sum_k(const float* __restrict__ ldj, double* __restrict__ acc) {
  double local = 0.0;
  for (int i = blockIdx.x * blockDim.x + threadIdx.x; i < BT; i += gridDim.x * blockDim.x)
    local += (double)ldj[i];
  local = block_reduce_d(local);
  if (threadIdx.x == 0) atomicAdd(acc + 1, local);
}

// z3 read from out[1..]; mv rows indexed t*1024+b
__global__ __launch_bounds__(256)
void post_all_k(const f16* __restrict__ mv, const float* __restrict__ out,
                double* __restrict__ acc) {
  const int n = BT * Zd;
  double local = 0.0;
  for (int i = blockIdx.x * blockDim.x + threadIdx.x; i < n; i += gridDim.x * blockDim.x) {
    const int k = i & 255;
    const int row = i >> 8;               // t*1024 + b
    const int t = row >> 10, b = row & 1023;
    const float mean = (float)mv[(size_t)row * 512 + k];
    const float lv = (float)mv[(size_t)row * 512 + 256 + k];
    const float zv = out[1 + ((size_t)b * 16 + t) * 256 + k];
    const float d = (zv - mean) * __expf(-lv);
    local += (double)(-0.5f * d * d - LOG_SQRT_2PI_F) - (double)lv;
  }
  local = block_reduce_d(local);
  if (threadIdx.x == 0) atomicAdd(acc + 0, local);
}

__global__ void finalize_k(const double* __restrict__ acc, float* __restrict__ out) {
  const double loglik = 0.0025 * acc[0] + acc[1];
  out[0] = (float)(-loglik / (double)Bb);
}

// ---------------- weight conversion ----------------
__global__ __launch_bounds__(256)
void cvt_k(const float* __restrict__ s, f16* __restrict__ d, int n) {
  for (int i = blockIdx.x * blockDim.x + threadIdx.x; i < n; i += gridDim.x * blockDim.x)
    d[i] = (f16)s[i];
}

// dst[l][2R][K]: rows<R from a[l], else b[l]
__global__ __launch_bounds__(256)
void cvt_cat_rows_k(const float* __restrict__ a, const float* __restrict__ b,
                    f16* __restrict__ d, int L, int R, int K) {
  const int n = L * 2 * R * K;
  for (int i = blockIdx.x * blockDim.x + threadIdx.x; i < n; i += gridDim.x * blockDim.x) {
    const int k = i % K;
    const int rem = i / K;
    const int r = rem % (2 * R);
    const int l = rem / (2 * R);
    const float v = (r < R) ? a[((size_t)l * R + r) * K + k]
                            : b[((size_t)l * R + (r - R)) * K + k];
    d[i] = (f16)v;
  }
}

// gate-interleaved fp16: d[n][k], K=ka+kb, old row = (n&3)*512 + (n>>2)
__global__ __launch_bounds__(256)
void cvt_int_k(const float* __restrict__ a, int ka, const float* __restrict__ b,
               int kb, f16* __restrict__ d, int N) {
  const int K = ka + kb;
  const int n_tot = N * K;
  for (int i = blockIdx.x * blockDim.x + threadIdx.x; i < n_tot; i += gridDim.x * blockDim.x) {
    const int k = i % K;
    const int n = i / K;
    const int row = (n & 3) * 512 + (n >> 2);
    const float v = (k < ka) ? a[(size_t)row * ka + k] : b[(size_t)row * kb + (k - ka)];
    d[i] = (f16)v;
  }
}

__global__ __launch_bounds__(256)
void bsum_int_k(const float* __restrict__ bih, const float* __restrict__ bhh,
                float* __restrict__ d) {
  const int i = blockIdx.x * blockDim.x + threadIdx.x;
  if (i < 2048) {
    const int row = (i & 3) * 512 + (i >> 2);
    d[i] = bih[row] + bhh[row];
  }
}

__global__ __launch_bounds__(256)
void fcat_k(const float* __restrict__ a, const float* __restrict__ b,
            float* __restrict__ d, int L, int R) {
  const int n = L * 2 * R;
  for (int i = blockIdx.x * blockDim.x + threadIdx.x; i < n; i += gridDim.x * blockDim.x) {
    const int c = i % (2 * R);
    const int l = i / (2 * R);
    d[i] = (c < R) ? a[(size_t)l * R + c] : b[(size_t)l * R + (c - R)];
  }
}

// ---------------- host launch ----------------
extern "C" void kernel_launch(void* const* d_in, const int* in_sizes, int n_in,
                              void* d_out, int out_size, void* d_ws, size_t ws_size,
                              hipStream_t stream) {
  (void)in_sizes; (void)n_in; (void)out_size; (void)ws_size;

  const float* nf    = (const float*)d_in[0];
  const float* sW1   = (const float*)d_in[1];
  const float* sb1   = (const float*)d_in[2];
  const float* sW2   = (const float*)d_in[3];
  const float* sb2   = (const float*)d_in[4];
  const float* sW3   = (const float*)d_in[5];
  const float* sb3   = (const float*)d_in[6];
  const float* tW1   = (const float*)d_in[7];
  const float* tb1   = (const float*)d_in[8];
  const float* tW2   = (const float*)d_in[9];
  const float* tb2   = (const float*)d_in[10];
  const float* tW3   = (const float*)d_in[11];
  const float* tb3   = (const float*)d_in[12];
  const float* l1Wih = (const float*)d_in[13];
  const float* l1Whh = (const float*)d_in[14];
  const float* l1bih = (const float*)d_in[15];
  const float* l1bhh = (const float*)d_in[16];
  const float* l2Wih = (const float*)d_in[17];
  const float* l2Whh = (const float*)d_in[18];
  const float* l2bih = (const float*)d_in[19];
  const float* l2bhh = (const float*)d_in[20];
  const float* mW    = (const float*)d_in[21];
  const float* mb    = (const float*)d_in[22];
  const float* lvW   = (const float*)d_in[23];
  const float* lvb   = (const float*)d_in[24];

  float* out = (float*)d_out;

  char* wsb = (char*)d_ws;
  size_t off = 0;
  auto alloc = [&](size_t bytes) -> char* {
    char* p = wsb + off;
    off += (bytes + 255) & ~(size_t)255;
    return p;
  };
  double* acc    = (double*)alloc(32);
  float*  z      = (float*)alloc((size_t)BT * Zd * 4);   // 16 MB
  f16*    inp512 = (f16*)alloc((size_t)BT * 512 * 2);    // 16 MB; LSTM: mvbuf
  f16*    hidA   = (f16*)alloc((size_t)BT * 1024 * 2);   // 32 MB; LSTM: xbuf (8 MB)
  f16*    hidB   = (f16*)alloc((size_t)BT * 1024 * 2);   // 32 MB
  f16*    s16b   = (f16*)alloc((size_t)BT * Zd * 2);     // 8 MB; LSTM state block
  f16*    t16b   = (f16*)alloc((size_t)BT * Zd * 2);     // 8 MB
  f16*    hall   = (f16*)alloc((size_t)BT * 512 * 2);    // 16 MB
  float*  ldj    = (float*)alloc((size_t)BT * 4);
  f16* w1cat = (f16*)alloc((size_t)9 * 1024 * 512 * 2);
  f16* w2s   = (f16*)alloc((size_t)9 * 512 * 512 * 2);
  f16* w2t   = (f16*)alloc((size_t)9 * 512 * 512 * 2);
  f16* w3s   = (f16*)alloc((size_t)9 * 256 * 512 * 2);
  f16* w3t   = (f16*)alloc((size_t)9 * 256 * 512 * 2);
  f16* wc1i  = (f16*)alloc((size_t)2048 * 768 * 2);
  f16* wc2i  = (f16*)alloc((size_t)2048 * 1024 * 2);
  f16* wmv   = (f16*)alloc((size_t)512 * 512 * 2);
  float* bcat1 = (float*)alloc((size_t)9 * 1024 * 4);
  float* bsum1 = (float*)alloc((size_t)2048 * 4);
  float* bsum2 = (float*)alloc((size_t)2048 * 4);
  float* bmv   = (float*)alloc((size_t)512 * 4);

  // LSTM-phase aliases
  constexpr size_t HS = (size_t)1024 * 512;
  f16*   xbuf  = hidA;                       // [16][1024][256] (8 MB of hidA)
  f16*   h1s0  = s16b;                       // ping-pong h1
  f16*   h1s1  = h1s0 + HS;
  f16*   h2s0  = h1s1 + HS;                  // ping-pong h2
  f16*   h2s1  = h2s0 + HS;
  float* c1    = (float*)(h2s1 + HS);        // fp32 [1024][512]
  float* c2    = c1 + HS;
  f16*   mvbuf = inp512;                     // [16384][512]
  f16*   h1s[2] = {h1s0, h1s1};
  f16*   h2s[2] = {h2s0, h2s1};

  // ---- weight conversions ----
  cvt_cat_rows_k<<<2048, 256, 0, stream>>>(sW1, tW1, w1cat, 9, 512, 512);
  cvt_k<<<2048, 256, 0, stream>>>(sW2, w2s, 9 * 512 * 512);
  cvt_k<<<2048, 256, 0, stream>>>(tW2, w2t, 9 * 512 * 512);
  cvt_k<<<1024, 256, 0, stream>>>(sW3, w3s, 9 * 256 * 512);
  cvt_k<<<1024, 256, 0, stream>>>(tW3, w3t, 9 * 256 * 512);
  cvt_int_k<<<1024, 256, 0, stream>>>(l1Wih, 256, l1Whh, 512, wc1i, 2048);
  cvt_int_k<<<1024, 256, 0, stream>>>(l2Wih, 512, l2Whh, 512, wc2i, 2048);
  cvt_cat_rows_k<<<256, 256, 0, stream>>>(mW, lvW, wmv, 1, 256, 512);
  fcat_k<<<16, 256, 0, stream>>>(sb1, tb1, bcat1, 9, 512);
  bsum_int_k<<<8, 256, 0, stream>>>(l1bih, l1bhh, bsum1);
  bsum_int_k<<<8, 256, 0, stream>>>(l2bih, l2bhh, bsum2);
  fcat_k<<<2, 256, 0, stream>>>(mb, lvb, bmv, 1, 256);

  hipMemsetAsync(acc, 0, 16, stream);
  hipMemsetAsync(ldj, 0, (size_t)BT * 4, stream);

  split_k<<<2048, 256, 0, stream>>>(nf, z, inp512);

  // ---- inverse flow: layers 8..0 ----
  for (int i = NL - 1; i >= 0; --i) {
    hgemm2_k<EPI_LEAKY, EPI_LEAKY><<<dim3(128, 8, 1), 256, 0, stream>>>(
        inp512, inp512, 512, w1cat + (size_t)i * 1024 * 512,
        w1cat + (size_t)i * 1024 * 512, 512, 512,
        bcat1 + i * 1024, bcat1 + i * 1024, hidA, hidA, 1024, 0);
    hgemm2_k<EPI_LEAKY, EPI_LEAKY><<<dim3(128, 4, 2), 256, 0, stream>>>(
        hidA, hidA + 512, 1024, w2s + (size_t)i * 512 * 512, w2t + (size_t)i * 512 * 512,
        512, 512, sb2 + i * 512, tb2 + i * 512, hidB, hidB + 512, 1024, 0);
    hgemm2_k<EPI_S, EPI_T><<<dim3(128, 2, 2), 256, 0, stream>>>(
        hidB, hidB + 512, 1024, w3s + (size_t)i * 256 * 512, w3t + (size_t)i * 256 * 512,
        512, 512, sb3 + i * 256, tb3 + i * 256, s16b, t16b, 256, i);
    if (i > 0) {
      flow_update_k<0><<<BT / 4, 256, 0, stream>>>(
          z, s16b, t16b, ldj, inp512, i, i - 1, nullptr, nullptr, nullptr);
      if (i - 1 == 0) prep0_k<<<2048, 256, 0, stream>>>(z, inp512);
    } else {
      flow_update_k<1><<<BT / 4, 256, 0, stream>>>(
          z, s16b, t16b, ldj, nullptr, 0, -1, out, xbuf, acc);
    }
  }

  ldj_sum_k<<<64, 256, 0, stream>>>(ldj, acc);

  // ---- LSTM prior: 16 paired dispatches ----
  hipMemsetAsync(h2s0, 0, HS * 2, stream);   // h2 state t=0
  hipMemsetAsync(c2, 0, HS * 4, stream);
  cell0_k<<<2048, 256, 0, stream>>>(bsum1, c1, h1s0);  // h1 state t=0, c1

  for (int t = 0; t < Tt; ++t) {
    const int pi = t & 1;
    const f16* xnext = (t < 15) ? (xbuf + (size_t)(t + 1) * 1024 * 256) : nullptr;
    pairgate_k<<<dim3(16, 32, (t < 15) ? 2 : 1), 256, 0, stream>>>(
        xnext, h1s[pi], h2s[pi], wc2i, wc1i, bsum2, bsum1,
        c1, c2, h1s[pi ^ 1], h2s[pi ^ 1], hall + (size_t)t * 1024 * 512);
  }

  hgemm2_k<EPI_MV, EPI_MV><<<dim3(128, 4, 1), 256, 0, stream>>>(
      hall, hall, 512, wmv, wmv, 512, 512, bmv, bmv, mvbuf, mvbuf, 512, 0);
  post_all_k<<<1024, 256, 0, stream>>>(mvbuf, out, acc);

  finalize_k<<<1, 1, 0, stream>>>(acc, out);
}